// Round 2
// baseline (564.346 us; speedup 1.0000x reference)
//
#include <hip/hip_runtime.h>
#include <cstdint>

#pragma clang fp contract(off)

constexpr int cB = 16;
constexpr int cN = 22743;
constexpr int cROW = 85;
constexpr int cK = 1000;
constexpr float CONF_T = 0.5f;
constexpr float NMS_T = 0.4f;

// ---------------- kernel 1: per-row score -> orderable uint key ----------------
// One wave per row. Lanes 0..63 read classes 0..63; lanes 0..15 also classes 64..79.
__global__ __launch_bounds__(256) void k_score(const float* __restrict__ in,
                                               unsigned* __restrict__ ukey) {
  int gw = (int)((blockIdx.x * 256u + threadIdx.x) >> 6);
  int lane = threadIdx.x & 63;
  if (gw >= cB * cN) return;
  const float* row = in + (size_t)gw * cROW;
  float v = row[5 + lane];
  if (lane < 16) v = fmaxf(v, row[69 + lane]);
#pragma unroll
  for (int m = 32; m >= 1; m >>= 1) v = fmaxf(v, __shfl_xor(v, m));
  if (lane == 0) {
    float obj = row[4];
    unsigned u = 0u;
    if (obj >= CONF_T) {
      float s = obj * v;                 // fp32 mul, matches np
      if (s > 0.0f) u = __float_as_uint(s);  // positive floats: bit order == value order
    }
    ukey[gw] = u;
  }
}

// ---------------- bitonic sorts (1024 elements, block of 1024 threads) ----------------
__device__ __forceinline__ void sort1024_u64_desc(unsigned long long* a, int tid) {
  for (int k = 2; k <= 1024; k <<= 1) {
    for (int j = k >> 1; j >= 1; j >>= 1) {
      __syncthreads();
      if (tid < 512) {
        int i = ((tid & ~(j - 1)) << 1) | (tid & (j - 1));
        int p = i | j;
        unsigned long long x = a[i], y = a[p];
        bool up = ((i & k) == 0);
        bool sw = up ? (x < y) : (x > y);   // descending overall
        if (sw) { a[i] = y; a[p] = x; }
      }
    }
  }
  __syncthreads();
}

__device__ __forceinline__ void sort1024_u32_asc(unsigned* a, int tid) {
  for (int k = 2; k <= 1024; k <<= 1) {
    for (int j = k >> 1; j >= 1; j >>= 1) {
      __syncthreads();
      if (tid < 512) {
        int i = ((tid & ~(j - 1)) << 1) | (tid & (j - 1));
        int p = i | j;
        unsigned x = a[i], y = a[p];
        bool up = ((i & k) == 0);
        bool sw = up ? (x > y) : (x < y);   // ascending overall
        if (sw) { a[i] = y; a[p] = x; }
      }
    }
  }
  __syncthreads();
}

// ---------------- kernel 2: exact top-1000 per image (radix-select + sort) ----------------
__global__ __launch_bounds__(1024) void k_topk(const unsigned* __restrict__ ukey,
                                               int* __restrict__ topidx) {
  __shared__ unsigned hist[256];
  __shared__ unsigned sh_bucket, sh_rank;
  __shared__ unsigned cnt_gt, cnt_eq;
  __shared__ unsigned long long skey[1024];
  __shared__ unsigned eqbuf[1024];
  int img = blockIdx.x;
  int tid = threadIdx.x;
  const unsigned* uk = ukey + (size_t)img * cN;

  unsigned prefix = 0;
  unsigned rank = cK;           // we want the cK-th largest
  for (int round = 0; round < 4; ++round) {
    int shift = 24 - 8 * round;
    if (tid < 256) hist[tid] = 0u;
    __syncthreads();
    for (int i = tid; i < cN; i += 1024) {
      unsigned u = uk[i];
      bool match = (round == 0);
      if (!match) match = ((u >> (32 - 8 * round)) == prefix);
      if (match) atomicAdd(&hist[(u >> shift) & 255u], 1u);
    }
    __syncthreads();
    if (tid == 0) {
      unsigned cum = 0;
      int b = 0;
      for (int d = 255; d >= 0; --d) {
        unsigned h = hist[d];
        if (cum + h >= rank) { b = d; break; }
        cum += h;
      }
      sh_bucket = (unsigned)b;
      sh_rank = rank - cum;
    }
    __syncthreads();
    prefix = (prefix << 8) | sh_bucket;
    rank = sh_rank;
    __syncthreads();
  }
  unsigned P = prefix;          // the cK-th largest key (0 => fewer than cK positives)

  if (tid == 0) { cnt_gt = 0u; cnt_eq = 0u; }
  skey[tid] = 0ull;
  eqbuf[tid] = 0xFFFFFFFFu;
  __syncthreads();
  for (int i = tid; i < cN; i += 1024) {
    unsigned u = uk[i];
    if (u > P) {
      unsigned pos = atomicAdd(&cnt_gt, 1u);   // guaranteed <= cK-1
      skey[pos] = ((unsigned long long)u << 32) |
                  (unsigned long long)(0xFFFFFFFFu - (unsigned)i);
    } else if (u == P && P != 0u) {
      unsigned pos = atomicAdd(&cnt_eq, 1u);
      if (pos < 1024u) eqbuf[pos] = (unsigned)i;
    }
  }
  __syncthreads();
  unsigned ng = cnt_gt;
  int need = cK - (int)ng;
  if (P != 0u) {
    sort1024_u32_asc(eqbuf, tid);            // ties at pivot: smallest indices win
    for (int t = tid; t < need; t += 1024) {
      unsigned idx = eqbuf[t];
      if (idx != 0xFFFFFFFFu)
        skey[ng + (unsigned)t] = ((unsigned long long)P << 32) |
                                 (unsigned long long)(0xFFFFFFFFu - idx);
    }
  }
  sort1024_u64_desc(skey, tid);              // score desc, index asc (lax.top_k order)
  if (tid < cK) {
    unsigned long long kk = skey[tid];
    unsigned u = (unsigned)(kk >> 32);
    int idx = (int)(0xFFFFFFFFu - (unsigned)(kk & 0xFFFFFFFFull));
    topidx[img * cK + tid] = (u > 0u) ? idx : -1;
  }
}

// ---------------- kernel 3: gather boxes/obj/conf/cls for top-K ----------------
__global__ __launch_bounds__(256) void k_gather(const float* __restrict__ in,
                                                const int* __restrict__ topidx,
                                                float4* __restrict__ boxes,
                                                float* __restrict__ area,
                                                float* __restrict__ objv,
                                                float* __restrict__ confv,
                                                int* __restrict__ clsv,
                                                int* __restrict__ validv) {
  int wid = (int)((blockIdx.x * 256u + threadIdx.x) >> 6);
  int lane = threadIdx.x & 63;
  if (wid >= cB * cK) return;
  int img = wid / cK;
  int idx = topidx[wid];
  if (idx < 0) {
    if (lane == 0) {
      boxes[wid] = make_float4(0.f, 0.f, 0.f, 0.f);
      area[wid] = 0.f; objv[wid] = 0.f; confv[wid] = 0.f;
      clsv[wid] = -1; validv[wid] = 0;
    }
    return;
  }
  const float* row = in + ((size_t)img * cN + (size_t)idx) * cROW;
  float v = row[5 + lane];
  int ci = lane;
  if (lane < 16) {
    float v2 = row[69 + lane];
    if (v2 > v) { v = v2; ci = 64 + lane; }   // strict >: lower class wins ties
  }
#pragma unroll
  for (int m = 1; m < 64; m <<= 1) {
    float ov = __shfl_xor(v, m);
    int oc = __shfl_xor(ci, m);
    if (ov > v || (ov == v && oc < ci)) { v = ov; ci = oc; }
  }
  if (lane == 0) {
    float cx = row[0], cy = row[1], w = row[2], h = row[3], ob = row[4];
    float hw = w * 0.5f, hh = h * 0.5f;      // *0.5 exact
    float x1 = cx - hw, y1 = cy - hh, x2 = cx + hw, y2 = cy + hh;
    boxes[wid] = make_float4(x1, y1, x2, y2);
    area[wid] = fmaxf(x2 - x1, 0.f) * fmaxf(y2 - y1, 0.f);
    objv[wid] = ob; confv[wid] = v; clsv[wid] = ci; validv[wid] = 1;
  }
}

// ---------------- kernel 4: suppress bitmask (1000x1000 bits per image) ----------------
__global__ __launch_bounds__(256) void k_suppress(const float4* __restrict__ boxes,
                                                  const float* __restrict__ area,
                                                  const int* __restrict__ clsv,
                                                  unsigned* __restrict__ S) {
  __shared__ float sx1[1024], sy1[1024], sx2[1024], sy2[1024], sar[1024];
  __shared__ int scls[1024];
  int img = blockIdx.x / 125;
  int rb = (blockIdx.x % 125) * 8;
  int tid = threadIdx.x;
  for (int i = tid; i < 1024; i += 256) {
    if (i < cK) {
      float4 b = boxes[img * cK + i];
      sx1[i] = b.x; sy1[i] = b.y; sx2[i] = b.z; sy2[i] = b.w;
      sar[i] = area[img * cK + i];
      scls[i] = clsv[img * cK + i];
    } else {
      sx1[i] = 0.f; sy1[i] = 0.f; sx2[i] = 0.f; sy2[i] = 0.f; sar[i] = 0.f;
      scls[i] = -2;
    }
  }
  __syncthreads();
  int i = rb + (tid >> 5);          // row 0..999
  int w = tid & 31;                 // word within row
  float bx1 = sx1[i], by1 = sy1[i], bx2 = sx2[i], by2 = sy2[i], ba = sar[i];
  int bc = scls[i];
  unsigned word = 0u;
  for (int bit = 0; bit < 32; ++bit) {
    int j = (w << 5) | bit;
    float xx1 = fmaxf(bx1, sx1[j]);
    float yy1 = fmaxf(by1, sy1[j]);
    float xx2 = fminf(bx2, sx2[j]);
    float yy2 = fminf(by2, sy2[j]);
    float inter = fmaxf(xx2 - xx1, 0.f) * fmaxf(yy2 - yy1, 0.f);
    float uni = ba + sar[j] - inter;
    float iou = inter / (uni + 1e-16f);     // IEEE div, matches np
    if (iou > NMS_T && bc == scls[j]) word |= (1u << bit);
  }
  S[((size_t)img * cK + i) * 32 + w] = word;
}

// ---------------- kernel 5: sequential greedy NMS + masked write ----------------
__global__ __launch_bounds__(64) void k_nms(const unsigned* __restrict__ S,
                                            const int* __restrict__ validv,
                                            const float4* __restrict__ boxes,
                                            const float* __restrict__ objv,
                                            const float* __restrict__ confv,
                                            const int* __restrict__ clsv,
                                            float* __restrict__ out) {
  __shared__ unsigned keep_sh[32];
  int img = blockIdx.x;
  int lane = threadIdx.x;
  unsigned kw = 0u;
  if (lane < 32) {
    for (int b = 0; b < 32; ++b) {
      int k = (lane << 5) + b;
      if (k < cK && validv[img * cK + k]) kw |= (1u << b);
    }
  }
  const unsigned* Si = S + (size_t)img * cK * 32;
  int w = lane & 31;
  // 8-deep register ring prefetch: row loads are independent of keep decisions
  unsigned ring[8];
#pragma unroll
  for (int d = 0; d < 8; ++d) ring[d] = Si[d * 32 + w];
  for (int i0 = 0; i0 < cK; i0 += 8) {
#pragma unroll
    for (int d = 0; d < 8; ++d) {
      int i = i0 + d;
      unsigned cur = ring[d];
      int pf = i + 8;
      ring[d] = (pf < cK) ? Si[pf * 32 + w] : 0u;
      unsigned ow = __shfl(kw, i >> 5);          // broadcast word owning bit i
      if ((ow >> (i & 31)) & 1u) {               // uniform branch
        int iw_ = i >> 5, ib = i & 31;
        unsigned jm = (w > iw_) ? 0xFFFFFFFFu
                      : (w < iw_) ? 0u
                      : ((ib == 31) ? 0u : (0xFFFFFFFFu << (ib + 1)));
        kw &= ~(cur & jm);                       // kill only j > i
      }
    }
  }
  if (lane < 32) keep_sh[lane] = kw;
  __syncthreads();
  for (int k = lane; k < cK; k += 64) {
    bool kp = ((keep_sh[k >> 5] >> (k & 31)) & 1u) != 0u;
    size_t o = ((size_t)img * cK + (size_t)k) * 7;
    if (kp) {
      float4 b = boxes[img * cK + k];
      out[o + 0] = b.x; out[o + 1] = b.y; out[o + 2] = b.z; out[o + 3] = b.w;
      out[o + 4] = objv[img * cK + k];
      out[o + 5] = confv[img * cK + k];
      out[o + 6] = (float)clsv[img * cK + k];
    } else {
      out[o + 0] = 0.f; out[o + 1] = 0.f; out[o + 2] = 0.f; out[o + 3] = 0.f;
      out[o + 4] = 0.f; out[o + 5] = 0.f; out[o + 6] = 0.f;
    }
  }
}

extern "C" void kernel_launch(void* const* d_in, const int* in_sizes, int n_in,
                              void* d_out, int out_size, void* d_ws, size_t ws_size,
                              hipStream_t stream) {
  const float* in = (const float*)d_in[0];
  float* out = (float*)d_out;
  char* ws = (char*)d_ws;
  size_t off = 0;
  auto take = [&](size_t bytes) {
    size_t r = off;
    off += (bytes + 255) & ~(size_t)255;
    return r;
  };
  unsigned* ukey = (unsigned*)(ws + take((size_t)cB * cN * 4));
  int* topidx = (int*)(ws + take((size_t)cB * cK * 4));
  float4* boxes = (float4*)(ws + take((size_t)cB * cK * 16));
  float* area = (float*)(ws + take((size_t)cB * cK * 4));
  float* objv = (float*)(ws + take((size_t)cB * cK * 4));
  float* confv = (float*)(ws + take((size_t)cB * cK * 4));
  int* clsv = (int*)(ws + take((size_t)cB * cK * 4));
  int* validv = (int*)(ws + take((size_t)cB * cK * 4));
  unsigned* S = (unsigned*)(ws + take((size_t)cB * cK * 32 * 4));

  int waves1 = cB * cN;                       // 363,888 rows, one wave each
  k_score<<<(waves1 * 64 + 255) / 256, 256, 0, stream>>>(in, ukey);
  k_topk<<<cB, 1024, 0, stream>>>(ukey, topidx);
  int waves3 = cB * cK;
  k_gather<<<(waves3 * 64 + 255) / 256, 256, 0, stream>>>(in, topidx, boxes, area,
                                                          objv, confv, clsv, validv);
  k_suppress<<<cB * 125, 256, 0, stream>>>(boxes, area, clsv, S);
  k_nms<<<cB, 64, 0, stream>>>(S, validv, boxes, objv, confv, clsv, out);
}

// Round 3
// 438.120 us; speedup vs baseline: 1.2881x; 1.2881x over previous
//
#include <hip/hip_runtime.h>
#include <cstdint>

#pragma clang fp contract(off)

constexpr int cB = 16;
constexpr int cN = 22743;
constexpr int cROW = 85;
constexpr int cK = 1000;
constexpr float CONF_T = 0.5f;
constexpr float NMS_T = 0.4f;

// ---------------- kernel 1: per-row score -> orderable uint key ----------------
__global__ __launch_bounds__(256) void k_score(const float* __restrict__ in,
                                               unsigned* __restrict__ ukey) {
  int gw = (int)((blockIdx.x * 256u + threadIdx.x) >> 6);
  int lane = threadIdx.x & 63;
  if (gw >= cB * cN) return;
  const float* row = in + (size_t)gw * cROW;
  float v = row[5 + lane];
  if (lane < 16) v = fmaxf(v, row[69 + lane]);
#pragma unroll
  for (int m = 32; m >= 1; m >>= 1) v = fmaxf(v, __shfl_xor(v, m));
  if (lane == 0) {
    float obj = row[4];
    unsigned u = 0u;
    if (obj >= CONF_T) {
      float s = obj * v;
      if (s > 0.0f) u = __float_as_uint(s);
    }
    ukey[gw] = u;
  }
}

// ---------------- bitonic sorts ----------------
__device__ __forceinline__ void sort1024_u64_desc(unsigned long long* a, int tid) {
  for (int k = 2; k <= 1024; k <<= 1) {
    for (int j = k >> 1; j >= 1; j >>= 1) {
      __syncthreads();
      if (tid < 512) {
        int i = ((tid & ~(j - 1)) << 1) | (tid & (j - 1));
        int p = i | j;
        unsigned long long x = a[i], y = a[p];
        bool up = ((i & k) == 0);
        bool sw = up ? (x < y) : (x > y);
        if (sw) { a[i] = y; a[p] = x; }
      }
    }
  }
  __syncthreads();
}

__device__ __forceinline__ void sort1024_u32_asc(unsigned* a, int tid) {
  for (int k = 2; k <= 1024; k <<= 1) {
    for (int j = k >> 1; j >= 1; j >>= 1) {
      __syncthreads();
      if (tid < 512) {
        int i = ((tid & ~(j - 1)) << 1) | (tid & (j - 1));
        int p = i | j;
        unsigned x = a[i], y = a[p];
        bool up = ((i & k) == 0);
        bool sw = up ? (x > y) : (x < y);
        if (sw) { a[i] = y; a[p] = x; }
      }
    }
  }
  __syncthreads();
}

// ---------------- kernel 2: exact top-1000 per image ----------------
__global__ __launch_bounds__(1024) void k_topk(const unsigned* __restrict__ ukey,
                                               int* __restrict__ topidx) {
  __shared__ unsigned hist[256];
  __shared__ unsigned suf[256];
  __shared__ unsigned sh_bucket, sh_rank;
  __shared__ unsigned cnt_gt, cnt_eq;
  __shared__ unsigned long long skey[1024];
  __shared__ unsigned eqbuf[1024];
  int img = blockIdx.x;
  int tid = threadIdx.x;
  int lane = tid & 63;
  const unsigned* uk = ukey + (size_t)img * cN;

  unsigned prefix = 0;
  unsigned rank = cK;
  for (int round = 0; round < 4; ++round) {
    int shift = 24 - 8 * round;
    if (tid < 256) hist[tid] = 0u;
    __syncthreads();
    for (int i0 = 0; i0 < cN; i0 += 1024) {
      int i = i0 + tid;
      unsigned u = (i < cN) ? uk[i] : 0u;
      bool valid = (i < cN);
      if (valid && round != 0) valid = ((u >> (32 - 8 * round)) == prefix);
      unsigned d = (u >> shift) & 255u;
      // wave match-any aggregation: one shared atomic per distinct digit per wave
      unsigned long long m = __ballot(valid);
#pragma unroll
      for (int b = 0; b < 8; ++b) {
        bool bit = (d >> b) & 1u;
        unsigned long long bal = __ballot(valid && bit);
        m &= bit ? bal : ~bal;
      }
      if (valid) {
        int ldr = __ffsll((long long)m) - 1;
        if (lane == ldr) atomicAdd(&hist[d], (unsigned)__popcll(m));
      }
    }
    __syncthreads();
    // parallel suffix sum over hist -> suf (inclusive)
    if (tid < 256) suf[tid] = hist[tid];
    __syncthreads();
    for (int s = 1; s < 256; s <<= 1) {
      unsigned v = 0;
      if (tid < 256) v = suf[tid] + ((tid + s < 256) ? suf[tid + s] : 0u);
      __syncthreads();
      if (tid < 256) suf[tid] = v;
      __syncthreads();
    }
    if (tid < 256) {
      unsigned Sd = suf[tid];
      unsigned Sn = (tid == 255) ? 0u : suf[tid + 1];
      if (Sd >= rank && Sn < rank) { sh_bucket = (unsigned)tid; sh_rank = rank - Sn; }
    }
    __syncthreads();
    prefix = (prefix << 8) | sh_bucket;
    rank = sh_rank;
    __syncthreads();
  }
  unsigned P = prefix;   // the cK-th largest key (0 => fewer than cK positives)

  if (tid == 0) { cnt_gt = 0u; cnt_eq = 0u; }
  skey[tid] = 0ull;
  eqbuf[tid] = 0xFFFFFFFFu;
  __syncthreads();
  for (int i0 = 0; i0 < cN; i0 += 1024) {
    int i = i0 + tid;
    unsigned u = (i < cN) ? uk[i] : 0u;
    bool gt = (i < cN) && (u > P);
    bool eq = (i < cN) && (u == P) && (P != 0u);
    unsigned long long mg = __ballot(gt);
    if (gt) {
      int ldr = __ffsll((long long)mg) - 1;
      unsigned base = 0;
      if (lane == ldr) base = atomicAdd(&cnt_gt, (unsigned)__popcll(mg));
      base = __shfl(base, ldr);
      unsigned pos = base + (unsigned)__popcll(mg & ((1ull << lane) - 1ull));
      skey[pos] = ((unsigned long long)u << 32) |
                  (unsigned long long)(0xFFFFFFFFu - (unsigned)i);
    }
    unsigned long long me = __ballot(eq);
    if (eq) {
      int ldr = __ffsll((long long)me) - 1;
      unsigned base = 0;
      if (lane == ldr) base = atomicAdd(&cnt_eq, (unsigned)__popcll(me));
      base = __shfl(base, ldr);
      unsigned pos = base + (unsigned)__popcll(me & ((1ull << lane) - 1ull));
      if (pos < 1024u) eqbuf[pos] = (unsigned)i;
    }
  }
  __syncthreads();
  unsigned ng = cnt_gt;
  unsigned ne = cnt_eq;
  int need = cK - (int)ng;
  if (P != 0u) {
    if ((int)ne > need) sort1024_u32_asc(eqbuf, tid);  // rare: more ties than slots
    // order within equal keys is fixed by the final u64 sort (via ~idx)
    for (int t = tid; t < need; t += 1024) {
      unsigned idx = eqbuf[t];
      if (idx != 0xFFFFFFFFu)
        skey[ng + (unsigned)t] = ((unsigned long long)P << 32) |
                                 (unsigned long long)(0xFFFFFFFFu - idx);
    }
  }
  sort1024_u64_desc(skey, tid);   // score desc, index asc (lax.top_k order)
  if (tid < cK) {
    unsigned long long kk = skey[tid];
    unsigned u = (unsigned)(kk >> 32);
    int idx = (int)(0xFFFFFFFFu - (unsigned)(kk & 0xFFFFFFFFull));
    topidx[img * cK + tid] = (u > 0u) ? idx : -1;
  }
}

// ---------------- kernel 3: gather ----------------
__global__ __launch_bounds__(256) void k_gather(const float* __restrict__ in,
                                                const int* __restrict__ topidx,
                                                float4* __restrict__ boxes,
                                                float* __restrict__ area,
                                                float* __restrict__ objv,
                                                float* __restrict__ confv,
                                                int* __restrict__ clsv,
                                                int* __restrict__ validv) {
  int wid = (int)((blockIdx.x * 256u + threadIdx.x) >> 6);
  int lane = threadIdx.x & 63;
  if (wid >= cB * cK) return;
  int img = wid / cK;
  int idx = topidx[wid];
  if (idx < 0) {
    if (lane == 0) {
      boxes[wid] = make_float4(0.f, 0.f, 0.f, 0.f);
      area[wid] = 0.f; objv[wid] = 0.f; confv[wid] = 0.f;
      clsv[wid] = -1; validv[wid] = 0;
    }
    return;
  }
  const float* row = in + ((size_t)img * cN + (size_t)idx) * cROW;
  float v = row[5 + lane];
  int ci = lane;
  if (lane < 16) {
    float v2 = row[69 + lane];
    if (v2 > v) { v = v2; ci = 64 + lane; }
  }
#pragma unroll
  for (int m = 1; m < 64; m <<= 1) {
    float ov = __shfl_xor(v, m);
    int oc = __shfl_xor(ci, m);
    if (ov > v || (ov == v && oc < ci)) { v = ov; ci = oc; }
  }
  if (lane == 0) {
    float cx = row[0], cy = row[1], w = row[2], h = row[3], ob = row[4];
    float hw = w * 0.5f, hh = h * 0.5f;
    float x1 = cx - hw, y1 = cy - hh, x2 = cx + hw, y2 = cy + hh;
    boxes[wid] = make_float4(x1, y1, x2, y2);
    area[wid] = fmaxf(x2 - x1, 0.f) * fmaxf(y2 - y1, 0.f);
    objv[wid] = ob; confv[wid] = v; clsv[wid] = ci; validv[wid] = 1;
  }
}

// ---------------- kernel 4: suppress bitmask, TRANSPOSED output ----------------
// St[img][w][i] (i padded to 1024): word w of suppress-row i.
__global__ __launch_bounds__(256) void k_suppress(const float4* __restrict__ boxes,
                                                  const float* __restrict__ area,
                                                  const int* __restrict__ clsv,
                                                  unsigned* __restrict__ St) {
  // +(i>>5) padding: inner-loop bank = (w+bit)%32 -> conflict-free
  __shared__ float sx1[1056], sy1[1056], sx2[1056], sy2[1056], sar[1056];
  __shared__ int scls[1056];
  int img = blockIdx.x >> 7;            // / 128
  int rb = (blockIdx.x & 127) * 8;      // 128 blocks x 8 rows = 1024 rows
  int tid = threadIdx.x;
  for (int i = tid; i < 1024; i += 256) {
    int p = i + (i >> 5);
    if (i < cK) {
      float4 b = boxes[img * cK + i];
      sx1[p] = b.x; sy1[p] = b.y; sx2[p] = b.z; sy2[p] = b.w;
      sar[p] = area[img * cK + i];
      scls[p] = clsv[img * cK + i];
    } else {
      sx1[p] = 0.f; sy1[p] = 0.f; sx2[p] = 0.f; sy2[p] = 0.f; sar[p] = 0.f;
      scls[p] = -2;
    }
  }
  __syncthreads();
  int i = rb + (tid >> 5);
  int w = tid & 31;
  int pi = i + (i >> 5);
  float bx1 = sx1[pi], by1 = sy1[pi], bx2 = sx2[pi], by2 = sy2[pi], ba = sar[pi];
  int bc = scls[pi];
  unsigned word = 0u;
#pragma unroll 4
  for (int bit = 0; bit < 32; ++bit) {
    int pj = 33 * w + bit;
    float xx1 = fmaxf(bx1, sx1[pj]);
    float yy1 = fmaxf(by1, sy1[pj]);
    float xx2 = fminf(bx2, sx2[pj]);
    float yy2 = fminf(by2, sy2[pj]);
    float inter = fmaxf(xx2 - xx1, 0.f) * fmaxf(yy2 - yy1, 0.f);
    float uni = ba + sar[pj] - inter;
    float iou = inter / (uni + 1e-16f);
    if (iou > NMS_T && bc == scls[pj]) word |= (1u << bit);
  }
  St[((size_t)(img * 32 + w)) * 1024 + (size_t)i] = word;
}

// ---------------- kernel 5: word-batched greedy NMS + masked write ----------------
__device__ __forceinline__ unsigned u4c(const uint4& v, int c) {
  return c == 0 ? v.x : c == 1 ? v.y : c == 2 ? v.z : v.w;
}

__global__ __launch_bounds__(64) void k_nms(const unsigned* __restrict__ St,
                                            const int* __restrict__ validv,
                                            const float4* __restrict__ boxes,
                                            const float* __restrict__ objv,
                                            const float* __restrict__ confv,
                                            const int* __restrict__ clsv,
                                            float* __restrict__ out) {
  __shared__ unsigned keep_sh[32];
  int img = blockIdx.x;
  int lane = threadIdx.x;
  if (lane < 32) {
    const uint4* colv = (const uint4*)(St + ((size_t)(img * 32 + lane)) * 1024);
    unsigned kw = 0u;
    for (int b = 0; b < 32; ++b) {
      int k = (lane << 5) + b;
      if (k < cK && validv[img * cK + k]) kw |= (1u << b);
    }
    uint4 bufA[8], bufB[8];
#pragma unroll
    for (int q = 0; q < 8; ++q) bufA[q] = colv[q];
    for (int b = 0; b < 32; ++b) {
      uint4* W = (b & 1) ? bufB : bufA;
      uint4* Nx = (b & 1) ? bufA : bufB;
      if (b < 31) {
#pragma unroll
        for (int q = 0; q < 8; ++q) Nx[q] = colv[8 * (b + 1) + q];
      }
      // owner lane b: serial 32 decisions for rows 32b..32b+31, all-local data
      unsigned dec = 0u;
      if (lane == b) {
        unsigned kwb = kw;
#pragma unroll
        for (int t = 0; t < 32; ++t) {
          if ((kwb >> t) & 1u) {
            dec |= (1u << t);
            unsigned rw = u4c(W[t >> 2], t & 3);
            unsigned mgt = (t == 31) ? 0u : (0xFFFFFFFFu << (t + 1));
            kwb &= ~(rw & mgt);   // kill only later rows within this word
          }
        }
        kw = kwb;
      }
      dec = __shfl(dec, b);       // broadcast the 32 decisions
      if (lane > b) {
#pragma unroll
        for (int t = 0; t < 32; ++t) {
          if ((dec >> t) & 1u) kw &= ~u4c(W[t >> 2], t & 3);
        }
      }
    }
    keep_sh[lane] = kw;
  }
  __syncthreads();
  for (int k = lane; k < cK; k += 64) {
    bool kp = ((keep_sh[k >> 5] >> (k & 31)) & 1u) != 0u;
    size_t o = ((size_t)img * cK + (size_t)k) * 7;
    if (kp) {
      float4 b = boxes[img * cK + k];
      out[o + 0] = b.x; out[o + 1] = b.y; out[o + 2] = b.z; out[o + 3] = b.w;
      out[o + 4] = objv[img * cK + k];
      out[o + 5] = confv[img * cK + k];
      out[o + 6] = (float)clsv[img * cK + k];
    } else {
      out[o + 0] = 0.f; out[o + 1] = 0.f; out[o + 2] = 0.f; out[o + 3] = 0.f;
      out[o + 4] = 0.f; out[o + 5] = 0.f; out[o + 6] = 0.f;
    }
  }
}

extern "C" void kernel_launch(void* const* d_in, const int* in_sizes, int n_in,
                              void* d_out, int out_size, void* d_ws, size_t ws_size,
                              hipStream_t stream) {
  const float* in = (const float*)d_in[0];
  float* out = (float*)d_out;
  char* ws = (char*)d_ws;
  size_t off = 0;
  auto take = [&](size_t bytes) {
    size_t r = off;
    off += (bytes + 255) & ~(size_t)255;
    return r;
  };
  unsigned* ukey = (unsigned*)(ws + take((size_t)cB * cN * 4));
  int* topidx = (int*)(ws + take((size_t)cB * cK * 4));
  float4* boxes = (float4*)(ws + take((size_t)cB * cK * 16));
  float* area = (float*)(ws + take((size_t)cB * cK * 4));
  float* objv = (float*)(ws + take((size_t)cB * cK * 4));
  float* confv = (float*)(ws + take((size_t)cB * cK * 4));
  int* clsv = (int*)(ws + take((size_t)cB * cK * 4));
  int* validv = (int*)(ws + take((size_t)cB * cK * 4));
  unsigned* St = (unsigned*)(ws + take((size_t)cB * 32 * 1024 * 4));

  int waves1 = cB * cN;
  k_score<<<(waves1 * 64 + 255) / 256, 256, 0, stream>>>(in, ukey);
  k_topk<<<cB, 1024, 0, stream>>>(ukey, topidx);
  int waves3 = cB * cK;
  k_gather<<<(waves3 * 64 + 255) / 256, 256, 0, stream>>>(in, topidx, boxes, area,
                                                          objv, confv, clsv, validv);
  k_suppress<<<cB * 128, 256, 0, stream>>>(boxes, area, clsv, St);
  k_nms<<<cB, 64, 0, stream>>>(St, validv, boxes, objv, confv, clsv, out);
}

// Round 4
// 358.035 us; speedup vs baseline: 1.5762x; 1.2237x over previous
//
#include <hip/hip_runtime.h>
#include <cstdint>

#pragma clang fp contract(off)

constexpr int cB = 16;
constexpr int cN = 22743;
constexpr int cROW = 85;
constexpr int cK = 1000;
constexpr float CONF_T = 0.5f;
constexpr float NMS_T = 0.4f;

// ---------------- kernel 1: per-row score -> orderable uint key ----------------
__global__ __launch_bounds__(256) void k_score(const float* __restrict__ in,
                                               unsigned* __restrict__ ukey) {
  int gw = (int)((blockIdx.x * 256u + threadIdx.x) >> 6);
  int lane = threadIdx.x & 63;
  if (gw >= cB * cN) return;
  const float* row = in + (size_t)gw * cROW;
  float v = row[5 + lane];
  if (lane < 16) v = fmaxf(v, row[69 + lane]);
#pragma unroll
  for (int m = 32; m >= 1; m >>= 1) v = fmaxf(v, __shfl_xor(v, m));
  if (lane == 0) {
    float obj = row[4];
    unsigned u = 0u;
    if (obj >= CONF_T) {
      float s = obj * v;
      if (s > 0.0f) u = __float_as_uint(s);
    }
    ukey[gw] = u;
  }
}

// ---------------- bitonic sorts ----------------
__device__ __forceinline__ void sort1024_u64_desc(unsigned long long* a, int tid) {
  for (int k = 2; k <= 1024; k <<= 1) {
    for (int j = k >> 1; j >= 1; j >>= 1) {
      __syncthreads();
      if (tid < 512) {
        int i = ((tid & ~(j - 1)) << 1) | (tid & (j - 1));
        int p = i | j;
        unsigned long long x = a[i], y = a[p];
        bool up = ((i & k) == 0);
        bool sw = up ? (x < y) : (x > y);
        if (sw) { a[i] = y; a[p] = x; }
      }
    }
  }
  __syncthreads();
}

__device__ __forceinline__ void sort1024_u32_asc(unsigned* a, int tid) {
  for (int k = 2; k <= 1024; k <<= 1) {
    for (int j = k >> 1; j >= 1; j >>= 1) {
      __syncthreads();
      if (tid < 512) {
        int i = ((tid & ~(j - 1)) << 1) | (tid & (j - 1));
        int p = i | j;
        unsigned x = a[i], y = a[p];
        bool up = ((i & k) == 0);
        bool sw = up ? (x > y) : (x < y);
        if (sw) { a[i] = y; a[p] = x; }
      }
    }
  }
  __syncthreads();
}

// ---------------- kernel 2: exact top-1000 per image ----------------
__global__ __launch_bounds__(1024) void k_topk(const unsigned* __restrict__ ukey,
                                               int* __restrict__ topidx) {
  __shared__ unsigned hist[256];
  __shared__ unsigned suf[256];
  __shared__ unsigned sh_bucket, sh_rank;
  __shared__ unsigned cnt_gt, cnt_eq;
  __shared__ unsigned long long skey[1024];
  __shared__ unsigned eqbuf[1024];
  int img = blockIdx.x;
  int tid = threadIdx.x;
  int lane = tid & 63;
  const unsigned* uk = ukey + (size_t)img * cN;

  unsigned prefix = 0;
  unsigned rank = cK;
  for (int round = 0; round < 4; ++round) {
    int shift = 24 - 8 * round;
    if (tid < 256) hist[tid] = 0u;
    __syncthreads();
    for (int i0 = 0; i0 < cN; i0 += 1024) {
      int i = i0 + tid;
      unsigned u = (i < cN) ? uk[i] : 0u;
      bool valid = (i < cN);
      if (valid && round != 0) valid = ((u >> (32 - 8 * round)) == prefix);
      unsigned d = (u >> shift) & 255u;
      // wave match-any aggregation: one shared atomic per distinct digit per wave
      unsigned long long m = __ballot(valid);
#pragma unroll
      for (int b = 0; b < 8; ++b) {
        bool bit = (d >> b) & 1u;
        unsigned long long bal = __ballot(valid && bit);
        m &= bit ? bal : ~bal;
      }
      if (valid) {
        int ldr = __ffsll((long long)m) - 1;
        if (lane == ldr) atomicAdd(&hist[d], (unsigned)__popcll(m));
      }
    }
    __syncthreads();
    // parallel suffix sum over hist -> suf (inclusive)
    if (tid < 256) suf[tid] = hist[tid];
    __syncthreads();
    for (int s = 1; s < 256; s <<= 1) {
      unsigned v = 0;
      if (tid < 256) v = suf[tid] + ((tid + s < 256) ? suf[tid + s] : 0u);
      __syncthreads();
      if (tid < 256) suf[tid] = v;
      __syncthreads();
    }
    if (tid < 256) {
      unsigned Sd = suf[tid];
      unsigned Sn = (tid == 255) ? 0u : suf[tid + 1];
      if (Sd >= rank && Sn < rank) { sh_bucket = (unsigned)tid; sh_rank = rank - Sn; }
    }
    __syncthreads();
    prefix = (prefix << 8) | sh_bucket;
    rank = sh_rank;
    __syncthreads();
  }
  unsigned P = prefix;   // the cK-th largest key (0 => fewer than cK positives)

  if (tid == 0) { cnt_gt = 0u; cnt_eq = 0u; }
  skey[tid] = 0ull;
  eqbuf[tid] = 0xFFFFFFFFu;
  __syncthreads();
  for (int i0 = 0; i0 < cN; i0 += 1024) {
    int i = i0 + tid;
    unsigned u = (i < cN) ? uk[i] : 0u;
    bool gt = (i < cN) && (u > P);
    bool eq = (i < cN) && (u == P) && (P != 0u);
    unsigned long long mg = __ballot(gt);
    if (gt) {
      int ldr = __ffsll((long long)mg) - 1;
      unsigned base = 0;
      if (lane == ldr) base = atomicAdd(&cnt_gt, (unsigned)__popcll(mg));
      base = __shfl(base, ldr);
      unsigned pos = base + (unsigned)__popcll(mg & ((1ull << lane) - 1ull));
      skey[pos] = ((unsigned long long)u << 32) |
                  (unsigned long long)(0xFFFFFFFFu - (unsigned)i);
    }
    unsigned long long me = __ballot(eq);
    if (eq) {
      int ldr = __ffsll((long long)me) - 1;
      unsigned base = 0;
      if (lane == ldr) base = atomicAdd(&cnt_eq, (unsigned)__popcll(me));
      base = __shfl(base, ldr);
      unsigned pos = base + (unsigned)__popcll(me & ((1ull << lane) - 1ull));
      if (pos < 1024u) eqbuf[pos] = (unsigned)i;
    }
  }
  __syncthreads();
  unsigned ng = cnt_gt;
  unsigned ne = cnt_eq;
  int need = cK - (int)ng;
  if (P != 0u) {
    if ((int)ne > need) sort1024_u32_asc(eqbuf, tid);  // rare: more ties than slots
    for (int t = tid; t < need; t += 1024) {
      unsigned idx = eqbuf[t];
      if (idx != 0xFFFFFFFFu)
        skey[ng + (unsigned)t] = ((unsigned long long)P << 32) |
                                 (unsigned long long)(0xFFFFFFFFu - idx);
    }
  }
  sort1024_u64_desc(skey, tid);   // score desc, index asc (lax.top_k order)
  if (tid < cK) {
    unsigned long long kk = skey[tid];
    unsigned u = (unsigned)(kk >> 32);
    int idx = (int)(0xFFFFFFFFu - (unsigned)(kk & 0xFFFFFFFFull));
    topidx[img * cK + tid] = (u > 0u) ? idx : -1;
  }
}

// ---------------- kernel 3: gather ----------------
__global__ __launch_bounds__(256) void k_gather(const float* __restrict__ in,
                                                const int* __restrict__ topidx,
                                                float4* __restrict__ boxes,
                                                float* __restrict__ area,
                                                float* __restrict__ objv,
                                                float* __restrict__ confv,
                                                int* __restrict__ clsv,
                                                int* __restrict__ validv) {
  int wid = (int)((blockIdx.x * 256u + threadIdx.x) >> 6);
  int lane = threadIdx.x & 63;
  if (wid >= cB * cK) return;
  int img = wid / cK;
  int idx = topidx[wid];
  if (idx < 0) {
    if (lane == 0) {
      boxes[wid] = make_float4(0.f, 0.f, 0.f, 0.f);
      area[wid] = 0.f; objv[wid] = 0.f; confv[wid] = 0.f;
      clsv[wid] = -1; validv[wid] = 0;
    }
    return;
  }
  const float* row = in + ((size_t)img * cN + (size_t)idx) * cROW;
  float v = row[5 + lane];
  int ci = lane;
  if (lane < 16) {
    float v2 = row[69 + lane];
    if (v2 > v) { v = v2; ci = 64 + lane; }
  }
#pragma unroll
  for (int m = 1; m < 64; m <<= 1) {
    float ov = __shfl_xor(v, m);
    int oc = __shfl_xor(ci, m);
    if (ov > v || (ov == v && oc < ci)) { v = ov; ci = oc; }
  }
  if (lane == 0) {
    float cx = row[0], cy = row[1], w = row[2], h = row[3], ob = row[4];
    float hw = w * 0.5f, hh = h * 0.5f;
    float x1 = cx - hw, y1 = cy - hh, x2 = cx + hw, y2 = cy + hh;
    boxes[wid] = make_float4(x1, y1, x2, y2);
    area[wid] = fmaxf(x2 - x1, 0.f) * fmaxf(y2 - y1, 0.f);
    objv[wid] = ob; confv[wid] = v; clsv[wid] = ci; validv[wid] = 1;
  }
}

// ---------------- kernel 4: suppress bitmask, TRANSPOSED output ----------------
// St[img][w][i] (i padded to 1024): word w of suppress-row i.
__global__ __launch_bounds__(256) void k_suppress(const float4* __restrict__ boxes,
                                                  const float* __restrict__ area,
                                                  const int* __restrict__ clsv,
                                                  unsigned* __restrict__ St) {
  // +(i>>5) padding: inner-loop bank = (w+bit)%32 -> conflict-free
  __shared__ float sx1[1056], sy1[1056], sx2[1056], sy2[1056], sar[1056];
  __shared__ int scls[1056];
  int img = blockIdx.x >> 7;            // / 128
  int rb = (blockIdx.x & 127) * 8;      // 128 blocks x 8 rows = 1024 rows
  int tid = threadIdx.x;
  for (int i = tid; i < 1024; i += 256) {
    int p = i + (i >> 5);
    if (i < cK) {
      float4 b = boxes[img * cK + i];
      sx1[p] = b.x; sy1[p] = b.y; sx2[p] = b.z; sy2[p] = b.w;
      sar[p] = area[img * cK + i];
      scls[p] = clsv[img * cK + i];
    } else {
      sx1[p] = 0.f; sy1[p] = 0.f; sx2[p] = 0.f; sy2[p] = 0.f; sar[p] = 0.f;
      scls[p] = -2;
    }
  }
  __syncthreads();
  int i = rb + (tid >> 5);
  int w = tid & 31;
  int pi = i + (i >> 5);
  float bx1 = sx1[pi], by1 = sy1[pi], bx2 = sx2[pi], by2 = sy2[pi], ba = sar[pi];
  int bc = scls[pi];
  unsigned word = 0u;
#pragma unroll 4
  for (int bit = 0; bit < 32; ++bit) {
    int pj = 33 * w + bit;
    float xx1 = fmaxf(bx1, sx1[pj]);
    float yy1 = fmaxf(by1, sy1[pj]);
    float xx2 = fminf(bx2, sx2[pj]);
    float yy2 = fminf(by2, sy2[pj]);
    float inter = fmaxf(xx2 - xx1, 0.f) * fmaxf(yy2 - yy1, 0.f);
    float uni = ba + sar[pj] - inter;
    float iou = inter / (uni + 1e-16f);
    if (iou > NMS_T && bc == scls[pj]) word |= (1u << bit);
  }
  St[((size_t)(img * 32 + w)) * 1024 + (size_t)i] = word;
}

// ---------------- kernel 5: word-batched greedy NMS + masked write ----------------
// All buffer accesses use compile-time indices (no runtime-selected pointer) so
// bufA/bufB stay in VGPRs. R3's pointer-switch version spilled to scratch
// (VGPR_Count=28 -> 131 us).
__device__ __forceinline__ unsigned u4c(const uint4& v, int c) {
  return c == 0 ? v.x : c == 1 ? v.y : c == 2 ? v.z : v.w;
}

__device__ __forceinline__ void nms_load(const uint4* __restrict__ colv, int b,
                                         uint4 (&buf)[8]) {
#pragma unroll
  for (int q = 0; q < 8; ++q) buf[q] = colv[8 * b + q];
}

__device__ __forceinline__ void nms_proc(int b, int lane, unsigned& kw,
                                         const uint4 (&W)[8]) {
  unsigned dec = 0u;
  if (lane == b) {
    unsigned kwb = kw;
#pragma unroll
    for (int t = 0; t < 32; ++t) {
      if ((kwb >> t) & 1u) {
        dec |= (1u << t);
        unsigned rw = u4c(W[t >> 2], t & 3);
        unsigned mgt = (t == 31) ? 0u : (0xFFFFFFFFu << (t + 1));
        kwb &= ~(rw & mgt);   // kill only later rows within this word
      }
    }
    kw = kwb;
  }
  dec = __shfl(dec, b);       // broadcast the 32 decisions
  if (lane > b) {
#pragma unroll
    for (int t = 0; t < 32; ++t) {
      unsigned sel = 0u - ((dec >> t) & 1u);
      kw &= ~(u4c(W[t >> 2], t & 3) & sel);
    }
  }
}

__global__ __launch_bounds__(64) void k_nms(const unsigned* __restrict__ St,
                                            const int* __restrict__ validv,
                                            const float4* __restrict__ boxes,
                                            const float* __restrict__ objv,
                                            const float* __restrict__ confv,
                                            const int* __restrict__ clsv,
                                            float* __restrict__ out) {
  __shared__ unsigned keep_sh[32];
  int img = blockIdx.x;
  int lane = threadIdx.x;
  if (lane < 32) {
    const uint4* colv = (const uint4*)(St + ((size_t)(img * 32 + lane)) * 1024);
    unsigned kw = 0u;
    for (int b = 0; b < 32; ++b) {
      int k = (lane << 5) + b;
      if (k < cK && validv[img * cK + k]) kw |= (1u << b);
    }
    uint4 bufA[8], bufB[8];
    nms_load(colv, 0, bufA);
    for (int b = 0; b < 32; b += 2) {
      if (b + 1 < 32) nms_load(colv, b + 1, bufB);
      nms_proc(b, lane, kw, bufA);
      if (b + 2 < 32) nms_load(colv, b + 2, bufA);
      nms_proc(b + 1, lane, kw, bufB);
    }
    keep_sh[lane] = kw;
  }
  __syncthreads();
  for (int k = lane; k < cK; k += 64) {
    bool kp = ((keep_sh[k >> 5] >> (k & 31)) & 1u) != 0u;
    size_t o = ((size_t)img * cK + (size_t)k) * 7;
    if (kp) {
      float4 b = boxes[img * cK + k];
      out[o + 0] = b.x; out[o + 1] = b.y; out[o + 2] = b.z; out[o + 3] = b.w;
      out[o + 4] = objv[img * cK + k];
      out[o + 5] = confv[img * cK + k];
      out[o + 6] = (float)clsv[img * cK + k];
    } else {
      out[o + 0] = 0.f; out[o + 1] = 0.f; out[o + 2] = 0.f; out[o + 3] = 0.f;
      out[o + 4] = 0.f; out[o + 5] = 0.f; out[o + 6] = 0.f;
    }
  }
}

extern "C" void kernel_launch(void* const* d_in, const int* in_sizes, int n_in,
                              void* d_out, int out_size, void* d_ws, size_t ws_size,
                              hipStream_t stream) {
  const float* in = (const float*)d_in[0];
  float* out = (float*)d_out;
  char* ws = (char*)d_ws;
  size_t off = 0;
  auto take = [&](size_t bytes) {
    size_t r = off;
    off += (bytes + 255) & ~(size_t)255;
    return r;
  };
  unsigned* ukey = (unsigned*)(ws + take((size_t)cB * cN * 4));
  int* topidx = (int*)(ws + take((size_t)cB * cK * 4));
  float4* boxes = (float4*)(ws + take((size_t)cB * cK * 16));
  float* area = (float*)(ws + take((size_t)cB * cK * 4));
  float* objv = (float*)(ws + take((size_t)cB * cK * 4));
  float* confv = (float*)(ws + take((size_t)cB * cK * 4));
  int* clsv = (int*)(ws + take((size_t)cB * cK * 4));
  int* validv = (int*)(ws + take((size_t)cB * cK * 4));
  unsigned* St = (unsigned*)(ws + take((size_t)cB * 32 * 1024 * 4));

  int waves1 = cB * cN;
  k_score<<<(waves1 * 64 + 255) / 256, 256, 0, stream>>>(in, ukey);
  k_topk<<<cB, 1024, 0, stream>>>(ukey, topidx);
  int waves3 = cB * cK;
  k_gather<<<(waves3 * 64 + 255) / 256, 256, 0, stream>>>(in, topidx, boxes, area,
                                                          objv, confv, clsv, validv);
  k_suppress<<<cB * 128, 256, 0, stream>>>(boxes, area, clsv, St);
  k_nms<<<cB, 64, 0, stream>>>(St, validv, boxes, objv, confv, clsv, out);
}

// Round 5
// 326.963 us; speedup vs baseline: 1.7260x; 1.0950x over previous
//
#include <hip/hip_runtime.h>
#include <cstdint>

#pragma clang fp contract(off)

constexpr int cB = 16;
constexpr int cN = 22743;
constexpr int cROW = 85;
constexpr int cK = 1000;
constexpr float CONF_T = 0.5f;
constexpr float NMS_T = 0.4f;

// ---------------- kernel 1: per-row score -> orderable uint key ----------------
// Stage 128 rows (2720 float4, 16B-aligned) into LDS with coalesced loads, then
// one THREAD per row reduces serially from LDS (no cross-lane ops). R4's
// wave-per-row version was issue-bound on 6-deep dependent shfl chains (84 us,
// 0.8 TB/s).
__global__ __launch_bounds__(256) void k_score(const float* __restrict__ in,
                                               unsigned* __restrict__ ukey) {
  __shared__ float sdata[10880];              // 128 rows x 85 floats = 43.52 KB
  constexpr int F4_PER_BLK = 2720;            // 10880 / 4
  constexpr int TOTAL_F4 = (cB * cN * cROW) / 4;  // 30,930,480 / 4 (divisible)
  int tid = threadIdx.x;
  const float4* gin4 = (const float4*)in;
  float4* s4 = (float4*)sdata;
  int base_f4 = blockIdx.x * F4_PER_BLK;
#pragma unroll
  for (int q = 0; q < 11; ++q) {
    int k = tid + 256 * q;
    if (k < F4_PER_BLK) {
      int g = base_f4 + k;
      if (g < TOTAL_F4) s4[k] = gin4[g];
    }
  }
  __syncthreads();
  if (tid < 128) {
    int r = blockIdx.x * 128 + tid;
    if (r < cB * cN) {
      const float* rowp = sdata + cROW * tid;
      float obj = rowp[4];
      float m = rowp[5];
#pragma unroll
      for (int j = 6; j < 85; ++j) m = fmaxf(m, rowp[j]);
      unsigned u = 0u;
      if (obj >= CONF_T) {
        float s = obj * m;
        if (s > 0.0f) u = __float_as_uint(s);
      }
      ukey[r] = u;
    }
  }
}

// ---------------- bitonic sorts ----------------
__device__ __forceinline__ void sort1024_u64_desc(unsigned long long* a, int tid) {
  for (int k = 2; k <= 1024; k <<= 1) {
    for (int j = k >> 1; j >= 1; j >>= 1) {
      __syncthreads();
      if (tid < 512) {
        int i = ((tid & ~(j - 1)) << 1) | (tid & (j - 1));
        int p = i | j;
        unsigned long long x = a[i], y = a[p];
        bool up = ((i & k) == 0);
        bool sw = up ? (x < y) : (x > y);
        if (sw) { a[i] = y; a[p] = x; }
      }
    }
  }
  __syncthreads();
}

__device__ __forceinline__ void sort1024_u32_asc(unsigned* a, int tid) {
  for (int k = 2; k <= 1024; k <<= 1) {
    for (int j = k >> 1; j >= 1; j >>= 1) {
      __syncthreads();
      if (tid < 512) {
        int i = ((tid & ~(j - 1)) << 1) | (tid & (j - 1));
        int p = i | j;
        unsigned x = a[i], y = a[p];
        bool up = ((i & k) == 0);
        bool sw = up ? (x > y) : (x < y);
        if (sw) { a[i] = y; a[p] = x; }
      }
    }
  }
  __syncthreads();
}

// ---------------- kernel 2: exact top-1000 per image ----------------
__global__ __launch_bounds__(1024) void k_topk(const unsigned* __restrict__ ukey,
                                               int* __restrict__ topidx) {
  __shared__ unsigned hist[256];
  __shared__ unsigned suf[256];
  __shared__ unsigned sh_bucket, sh_rank;
  __shared__ unsigned cnt_gt, cnt_eq;
  __shared__ unsigned long long skey[1024];
  __shared__ unsigned eqbuf[1024];
  int img = blockIdx.x;
  int tid = threadIdx.x;
  int lane = tid & 63;
  const unsigned* uk = ukey + (size_t)img * cN;

  unsigned prefix = 0;
  unsigned rank = cK;
  for (int round = 0; round < 4; ++round) {
    int shift = 24 - 8 * round;
    if (tid < 256) hist[tid] = 0u;
    __syncthreads();
    for (int i0 = 0; i0 < cN; i0 += 1024) {
      int i = i0 + tid;
      unsigned u = (i < cN) ? uk[i] : 0u;
      bool valid = (i < cN);
      if (valid && round != 0) valid = ((u >> (32 - 8 * round)) == prefix);
      unsigned d = (u >> shift) & 255u;
      // wave match-any aggregation: one shared atomic per distinct digit per wave
      unsigned long long m = __ballot(valid);
#pragma unroll
      for (int b = 0; b < 8; ++b) {
        bool bit = (d >> b) & 1u;
        unsigned long long bal = __ballot(valid && bit);
        m &= bit ? bal : ~bal;
      }
      if (valid) {
        int ldr = __ffsll((long long)m) - 1;
        if (lane == ldr) atomicAdd(&hist[d], (unsigned)__popcll(m));
      }
    }
    __syncthreads();
    // parallel suffix sum over hist -> suf (inclusive)
    if (tid < 256) suf[tid] = hist[tid];
    __syncthreads();
    for (int s = 1; s < 256; s <<= 1) {
      unsigned v = 0;
      if (tid < 256) v = suf[tid] + ((tid + s < 256) ? suf[tid + s] : 0u);
      __syncthreads();
      if (tid < 256) suf[tid] = v;
      __syncthreads();
    }
    if (tid < 256) {
      unsigned Sd = suf[tid];
      unsigned Sn = (tid == 255) ? 0u : suf[tid + 1];
      if (Sd >= rank && Sn < rank) { sh_bucket = (unsigned)tid; sh_rank = rank - Sn; }
    }
    __syncthreads();
    prefix = (prefix << 8) | sh_bucket;
    rank = sh_rank;
    __syncthreads();
  }
  unsigned P = prefix;   // the cK-th largest key (0 => fewer than cK positives)

  if (tid == 0) { cnt_gt = 0u; cnt_eq = 0u; }
  skey[tid] = 0ull;
  eqbuf[tid] = 0xFFFFFFFFu;
  __syncthreads();
  for (int i0 = 0; i0 < cN; i0 += 1024) {
    int i = i0 + tid;
    unsigned u = (i < cN) ? uk[i] : 0u;
    bool gt = (i < cN) && (u > P);
    bool eq = (i < cN) && (u == P) && (P != 0u);
    unsigned long long mg = __ballot(gt);
    if (gt) {
      int ldr = __ffsll((long long)mg) - 1;
      unsigned base = 0;
      if (lane == ldr) base = atomicAdd(&cnt_gt, (unsigned)__popcll(mg));
      base = __shfl(base, ldr);
      unsigned pos = base + (unsigned)__popcll(mg & ((1ull << lane) - 1ull));
      skey[pos] = ((unsigned long long)u << 32) |
                  (unsigned long long)(0xFFFFFFFFu - (unsigned)i);
    }
    unsigned long long me = __ballot(eq);
    if (eq) {
      int ldr = __ffsll((long long)me) - 1;
      unsigned base = 0;
      if (lane == ldr) base = atomicAdd(&cnt_eq, (unsigned)__popcll(me));
      base = __shfl(base, ldr);
      unsigned pos = base + (unsigned)__popcll(me & ((1ull << lane) - 1ull));
      if (pos < 1024u) eqbuf[pos] = (unsigned)i;
    }
  }
  __syncthreads();
  unsigned ng = cnt_gt;
  unsigned ne = cnt_eq;
  int need = cK - (int)ng;
  if (P != 0u) {
    if ((int)ne > need) sort1024_u32_asc(eqbuf, tid);  // rare: more ties than slots
    for (int t = tid; t < need; t += 1024) {
      unsigned idx = eqbuf[t];
      if (idx != 0xFFFFFFFFu)
        skey[ng + (unsigned)t] = ((unsigned long long)P << 32) |
                                 (unsigned long long)(0xFFFFFFFFu - idx);
    }
  }
  sort1024_u64_desc(skey, tid);   // score desc, index asc (lax.top_k order)
  if (tid < cK) {
    unsigned long long kk = skey[tid];
    unsigned u = (unsigned)(kk >> 32);
    int idx = (int)(0xFFFFFFFFu - (unsigned)(kk & 0xFFFFFFFFull));
    topidx[img * cK + tid] = (u > 0u) ? idx : -1;
  }
}

// ---------------- kernel 3: gather ----------------
__global__ __launch_bounds__(256) void k_gather(const float* __restrict__ in,
                                                const int* __restrict__ topidx,
                                                float4* __restrict__ boxes,
                                                float* __restrict__ area,
                                                float* __restrict__ objv,
                                                float* __restrict__ confv,
                                                int* __restrict__ clsv,
                                                int* __restrict__ validv) {
  int wid = (int)((blockIdx.x * 256u + threadIdx.x) >> 6);
  int lane = threadIdx.x & 63;
  if (wid >= cB * cK) return;
  int img = wid / cK;
  int idx = topidx[wid];
  if (idx < 0) {
    if (lane == 0) {
      boxes[wid] = make_float4(0.f, 0.f, 0.f, 0.f);
      area[wid] = 0.f; objv[wid] = 0.f; confv[wid] = 0.f;
      clsv[wid] = -1; validv[wid] = 0;
    }
    return;
  }
  const float* row = in + ((size_t)img * cN + (size_t)idx) * cROW;
  float v = row[5 + lane];
  int ci = lane;
  if (lane < 16) {
    float v2 = row[69 + lane];
    if (v2 > v) { v = v2; ci = 64 + lane; }
  }
#pragma unroll
  for (int m = 1; m < 64; m <<= 1) {
    float ov = __shfl_xor(v, m);
    int oc = __shfl_xor(ci, m);
    if (ov > v || (ov == v && oc < ci)) { v = ov; ci = oc; }
  }
  if (lane == 0) {
    float cx = row[0], cy = row[1], w = row[2], h = row[3], ob = row[4];
    float hw = w * 0.5f, hh = h * 0.5f;
    float x1 = cx - hw, y1 = cy - hh, x2 = cx + hw, y2 = cy + hh;
    boxes[wid] = make_float4(x1, y1, x2, y2);
    area[wid] = fmaxf(x2 - x1, 0.f) * fmaxf(y2 - y1, 0.f);
    objv[wid] = ob; confv[wid] = v; clsv[wid] = ci; validv[wid] = 1;
  }
}

// ---------------- kernel 4: suppress bitmask, TRANSPOSED output ----------------
// St[img][w][i] (i padded to 1024): word w of suppress-row i.
__global__ __launch_bounds__(256) void k_suppress(const float4* __restrict__ boxes,
                                                  const float* __restrict__ area,
                                                  const int* __restrict__ clsv,
                                                  unsigned* __restrict__ St) {
  // +(i>>5) padding: inner-loop bank = (w+bit)%32 -> conflict-free
  __shared__ float sx1[1056], sy1[1056], sx2[1056], sy2[1056], sar[1056];
  __shared__ int scls[1056];
  int img = blockIdx.x >> 7;            // / 128
  int rb = (blockIdx.x & 127) * 8;      // 128 blocks x 8 rows = 1024 rows
  int tid = threadIdx.x;
  for (int i = tid; i < 1024; i += 256) {
    int p = i + (i >> 5);
    if (i < cK) {
      float4 b = boxes[img * cK + i];
      sx1[p] = b.x; sy1[p] = b.y; sx2[p] = b.z; sy2[p] = b.w;
      sar[p] = area[img * cK + i];
      scls[p] = clsv[img * cK + i];
    } else {
      sx1[p] = 0.f; sy1[p] = 0.f; sx2[p] = 0.f; sy2[p] = 0.f; sar[p] = 0.f;
      scls[p] = -2;
    }
  }
  __syncthreads();
  int i = rb + (tid >> 5);
  int w = tid & 31;
  int pi = i + (i >> 5);
  float bx1 = sx1[pi], by1 = sy1[pi], bx2 = sx2[pi], by2 = sy2[pi], ba = sar[pi];
  int bc = scls[pi];
  unsigned word = 0u;
#pragma unroll 4
  for (int bit = 0; bit < 32; ++bit) {
    int pj = 33 * w + bit;
    float xx1 = fmaxf(bx1, sx1[pj]);
    float yy1 = fmaxf(by1, sy1[pj]);
    float xx2 = fminf(bx2, sx2[pj]);
    float yy2 = fminf(by2, sy2[pj]);
    float inter = fmaxf(xx2 - xx1, 0.f) * fmaxf(yy2 - yy1, 0.f);
    float uni = ba + sar[pj] - inter;
    float iou = inter / (uni + 1e-16f);
    if (iou > NMS_T && bc == scls[pj]) word |= (1u << bit);
  }
  St[((size_t)(img * 32 + w)) * 1024 + (size_t)i] = word;
}

// ---------------- kernel 5: word-batched greedy NMS + masked write ----------------
// All buffer accesses use compile-time indices (no runtime-selected pointer) so
// bufA/bufB stay in VGPRs. R3's pointer-switch version spilled to scratch
// (VGPR_Count=28 -> 131 us).
__device__ __forceinline__ unsigned u4c(const uint4& v, int c) {
  return c == 0 ? v.x : c == 1 ? v.y : c == 2 ? v.z : v.w;
}

__device__ __forceinline__ void nms_load(const uint4* __restrict__ colv, int b,
                                         uint4 (&buf)[8]) {
#pragma unroll
  for (int q = 0; q < 8; ++q) buf[q] = colv[8 * b + q];
}

__device__ __forceinline__ void nms_proc(int b, int lane, unsigned& kw,
                                         const uint4 (&W)[8]) {
  unsigned dec = 0u;
  if (lane == b) {
    unsigned kwb = kw;
#pragma unroll
    for (int t = 0; t < 32; ++t) {
      if ((kwb >> t) & 1u) {
        dec |= (1u << t);
        unsigned rw = u4c(W[t >> 2], t & 3);
        unsigned mgt = (t == 31) ? 0u : (0xFFFFFFFFu << (t + 1));
        kwb &= ~(rw & mgt);   // kill only later rows within this word
      }
    }
    kw = kwb;
  }
  dec = __shfl(dec, b);       // broadcast the 32 decisions
  if (lane > b) {
#pragma unroll
    for (int t = 0; t < 32; ++t) {
      unsigned sel = 0u - ((dec >> t) & 1u);
      kw &= ~(u4c(W[t >> 2], t & 3) & sel);
    }
  }
}

__global__ __launch_bounds__(64) void k_nms(const unsigned* __restrict__ St,
                                            const int* __restrict__ validv,
                                            const float4* __restrict__ boxes,
                                            const float* __restrict__ objv,
                                            const float* __restrict__ confv,
                                            const int* __restrict__ clsv,
                                            float* __restrict__ out) {
  __shared__ unsigned keep_sh[32];
  int img = blockIdx.x;
  int lane = threadIdx.x;
  if (lane < 32) {
    const uint4* colv = (const uint4*)(St + ((size_t)(img * 32 + lane)) * 1024);
    unsigned kw = 0u;
    for (int b = 0; b < 32; ++b) {
      int k = (lane << 5) + b;
      if (k < cK && validv[img * cK + k]) kw |= (1u << b);
    }
    uint4 bufA[8], bufB[8];
    nms_load(colv, 0, bufA);
    for (int b = 0; b < 32; b += 2) {
      if (b + 1 < 32) nms_load(colv, b + 1, bufB);
      nms_proc(b, lane, kw, bufA);
      if (b + 2 < 32) nms_load(colv, b + 2, bufA);
      nms_proc(b + 1, lane, kw, bufB);
    }
    keep_sh[lane] = kw;
  }
  __syncthreads();
  for (int k = lane; k < cK; k += 64) {
    bool kp = ((keep_sh[k >> 5] >> (k & 31)) & 1u) != 0u;
    size_t o = ((size_t)img * cK + (size_t)k) * 7;
    if (kp) {
      float4 b = boxes[img * cK + k];
      out[o + 0] = b.x; out[o + 1] = b.y; out[o + 2] = b.z; out[o + 3] = b.w;
      out[o + 4] = objv[img * cK + k];
      out[o + 5] = confv[img * cK + k];
      out[o + 6] = (float)clsv[img * cK + k];
    } else {
      out[o + 0] = 0.f; out[o + 1] = 0.f; out[o + 2] = 0.f; out[o + 3] = 0.f;
      out[o + 4] = 0.f; out[o + 5] = 0.f; out[o + 6] = 0.f;
    }
  }
}

extern "C" void kernel_launch(void* const* d_in, const int* in_sizes, int n_in,
                              void* d_out, int out_size, void* d_ws, size_t ws_size,
                              hipStream_t stream) {
  const float* in = (const float*)d_in[0];
  float* out = (float*)d_out;
  char* ws = (char*)d_ws;
  size_t off = 0;
  auto take = [&](size_t bytes) {
    size_t r = off;
    off += (bytes + 255) & ~(size_t)255;
    return r;
  };
  unsigned* ukey = (unsigned*)(ws + take((size_t)cB * cN * 4));
  int* topidx = (int*)(ws + take((size_t)cB * cK * 4));
  float4* boxes = (float4*)(ws + take((size_t)cB * cK * 16));
  float* area = (float*)(ws + take((size_t)cB * cK * 4));
  float* objv = (float*)(ws + take((size_t)cB * cK * 4));
  float* confv = (float*)(ws + take((size_t)cB * cK * 4));
  int* clsv = (int*)(ws + take((size_t)cB * cK * 4));
  int* validv = (int*)(ws + take((size_t)cB * cK * 4));
  unsigned* St = (unsigned*)(ws + take((size_t)cB * 32 * 1024 * 4));

  int nrows = cB * cN;
  int blocks1 = (nrows + 127) / 128;          // 128 rows per block
  k_score<<<blocks1, 256, 0, stream>>>(in, ukey);
  k_topk<<<cB, 1024, 0, stream>>>(ukey, topidx);
  int waves3 = cB * cK;
  k_gather<<<(waves3 * 64 + 255) / 256, 256, 0, stream>>>(in, topidx, boxes, area,
                                                          objv, confv, clsv, validv);
  k_suppress<<<cB * 128, 256, 0, stream>>>(boxes, area, clsv, St);
  k_nms<<<cB, 64, 0, stream>>>(St, validv, boxes, objv, confv, clsv, out);
}

// Round 6
// 284.718 us; speedup vs baseline: 1.9821x; 1.1484x over previous
//
#include <hip/hip_runtime.h>
#include <cstdint>

#pragma clang fp contract(off)

constexpr int cB = 16;
constexpr int cN = 22743;
constexpr int cROW = 85;
constexpr int cK = 1000;
constexpr float CONF_T = 0.5f;
constexpr float NMS_T = 0.4f;

// ---------------- kernel 1: per-row score -> orderable uint key ----------------
// Stage 128 rows (2720 float4, 16B-aligned) into LDS with coalesced loads, then
// one THREAD per row reduces serially from LDS (no cross-lane ops). R4's
// wave-per-row version was issue-bound on 6-deep dependent shfl chains (84 us,
// 0.8 TB/s).
__global__ __launch_bounds__(256) void k_score(const float* __restrict__ in,
                                               unsigned* __restrict__ ukey) {
  __shared__ float sdata[10880];              // 128 rows x 85 floats = 43.52 KB
  constexpr int F4_PER_BLK = 2720;            // 10880 / 4
  constexpr int TOTAL_F4 = (cB * cN * cROW) / 4;
  int tid = threadIdx.x;
  const float4* gin4 = (const float4*)in;
  float4* s4 = (float4*)sdata;
  int base_f4 = blockIdx.x * F4_PER_BLK;
#pragma unroll
  for (int q = 0; q < 11; ++q) {
    int k = tid + 256 * q;
    if (k < F4_PER_BLK) {
      int g = base_f4 + k;
      if (g < TOTAL_F4) s4[k] = gin4[g];
    }
  }
  __syncthreads();
  if (tid < 128) {
    int r = blockIdx.x * 128 + tid;
    if (r < cB * cN) {
      const float* rowp = sdata + cROW * tid;
      float obj = rowp[4];
      float m = rowp[5];
#pragma unroll
      for (int j = 6; j < 85; ++j) m = fmaxf(m, rowp[j]);
      unsigned u = 0u;
      if (obj >= CONF_T) {
        float s = obj * m;
        if (s > 0.0f) u = __float_as_uint(s);
      }
      ukey[r] = u;
    }
  }
}

// ---------------- bitonic sort (u32 asc; only for the rare exact-tie path) ----
__device__ __forceinline__ void sort1024_u32_asc(unsigned* a, int tid) {
  for (int k = 2; k <= 1024; k <<= 1) {
    for (int j = k >> 1; j >= 1; j >>= 1) {
      __syncthreads();
      if (tid < 512) {
        int i = ((tid & ~(j - 1)) << 1) | (tid & (j - 1));
        int p = i | j;
        unsigned x = a[i], y = a[p];
        bool up = ((i & k) == 0);
        bool sw = up ? (x > y) : (x < y);
        if (sw) { a[i] = y; a[p] = x; }
      }
    }
  }
  __syncthreads();
}

// ---------------- kernel 2: exact top-1000 per image ----------------
// 11-bit histogram radix-select (1 round typical; refines to 22/32 bits only if
// the candidate set exceeds 1024), single-predicate compaction, then
// rank-by-count over <=1024 distinct u64 keys (replaces R5's 55-stage bitonic
// sort + 4x 9-ballot histogram rounds that made this 81 us at 2.7% occupancy).
__global__ __launch_bounds__(1024) void k_topk(const unsigned* __restrict__ ukey,
                                               int* __restrict__ topidx) {
  __shared__ unsigned hist[2048];             // 8 KB
  __shared__ unsigned psum[1024];             // 4 KB
  __shared__ unsigned long long cand[1024];   // 8 KB
  __shared__ unsigned eqbuf[1024];            // 4 KB (tie path only)
  __shared__ unsigned sh_T, sh_newrank, sh_E, sh_cnt;
  int img = blockIdx.x;
  int tid = threadIdx.x;
  int lane = tid & 63;
  const unsigned* uk = ukey + (size_t)img * cN;

  unsigned prefix = 0;
  int bits = 0;
  unsigned rank = cK;
  unsigned gtc = 0;   // count of keys strictly greater than current prefix block
  unsigned E = 0;     // count of keys equal to current prefix block

  for (int r = 0; r < 3; ++r) {
    int nb = (r < 2) ? 11 : 10;
    int shift = 32 - bits - nb;
    hist[tid] = 0u; hist[tid + 1024] = 0u;
    __syncthreads();
    for (int i0 = 0; i0 < cN; i0 += 1024) {
      int i = i0 + tid;
      unsigned u = (i < cN) ? uk[i] : 0u;
      bool inr = (i < cN);
      bool match = inr && (bits == 0 || (u >> (32 - bits)) == prefix);
      bool isz = match && (u == 0u);
      bool nz = match && (u != 0u);
      // zeros all hit bin 0 -> aggregate to one atomic per wave
      unsigned long long mz = __ballot(isz);
      if (isz && lane == (__ffsll((long long)mz) - 1))
        atomicAdd(&hist[0], (unsigned)__popcll(mz));
      if (nz) atomicAdd(&hist[(u >> shift) & ((1u << nb) - 1u)], 1u);
    }
    __syncthreads();
    // suffix sums over 2048 bins via 1024 pair-sums (Hillis-Steele, 10 steps)
    unsigned h0 = hist[2 * tid];
    unsigned h1 = hist[2 * tid + 1];
    psum[tid] = h0 + h1;
    __syncthreads();
    for (int s = 1; s < 1024; s <<= 1) {
      unsigned v = psum[tid] + ((tid + s < 1024) ? psum[tid + s] : 0u);
      __syncthreads();
      psum[tid] = v;
      __syncthreads();
    }
    unsigned St = psum[tid];
    unsigned Stn = (tid < 1023) ? psum[tid + 1] : 0u;
    unsigned sufE = St;        // suffix(2*tid)
    unsigned sufO = St - h0;   // suffix(2*tid+1)
    // unique pivot bin T: suffix(T) >= rank > suffix(T+1)
    if (sufE >= rank && sufO < rank) { sh_T = 2u * tid; sh_newrank = rank - sufO; sh_E = h0; }
    if (sufO >= rank && Stn < rank) { sh_T = 2u * tid + 1u; sh_newrank = rank - Stn; sh_E = h1; }
    __syncthreads();
    unsigned T = sh_T;
    unsigned nr = sh_newrank;
    E = sh_E;
    gtc += rank - nr;          // suffix(T+1) at this level
    rank = nr;
    prefix = (prefix << nb) | T;
    bits += nb;
    __syncthreads();           // hist reused next round
    if (gtc + E <= 1024u) break;
  }

  bool tiepath = (gtc + E > 1024u);   // only possible at bits==32 (exact ties)
  unsigned pivotLo = (bits >= 32) ? prefix : (prefix << (32 - bits));
  cand[tid] = (unsigned long long)tid;   // distinct filler keys, high32 = 0
  eqbuf[tid] = 0xFFFFFFFFu;
  if (tid == 0) sh_cnt = 0u;
  __syncthreads();

  if (!tiepath) {
    for (int i0 = 0; i0 < cN; i0 += 1024) {
      int i = i0 + tid;
      unsigned u = (i < cN) ? uk[i] : 0u;
      bool m = (i < cN) && (u >= pivotLo);
      unsigned long long mb = __ballot(m);
      if (m) {
        int ldr = __ffsll((long long)mb) - 1;
        unsigned base = 0;
        if (lane == ldr) base = atomicAdd(&sh_cnt, (unsigned)__popcll(mb));
        base = __shfl(base, ldr);
        unsigned pos = base + (unsigned)__popcll(mb & ((1ull << lane) - 1ull));
        if (pos < 1024u)
          cand[pos] = ((unsigned long long)u << 32) |
                      (unsigned long long)(0xFFFFFFFFu - (unsigned)i);
      }
    }
    __syncthreads();
  } else {
    // exact-tie fallback: u > P into cand, u == P smallest indices appended
    unsigned P = prefix;
    for (int i0 = 0; i0 < cN; i0 += 1024) {
      int i = i0 + tid;
      unsigned u = (i < cN) ? uk[i] : 0u;
      bool gt = (i < cN) && (u > P);
      unsigned long long mb = __ballot(gt);
      if (gt) {
        int ldr = __ffsll((long long)mb) - 1;
        unsigned base = 0;
        if (lane == ldr) base = atomicAdd(&sh_cnt, (unsigned)__popcll(mb));
        base = __shfl(base, ldr);
        unsigned pos = base + (unsigned)__popcll(mb & ((1ull << lane) - 1ull));
        if (pos < 1024u)
          cand[pos] = ((unsigned long long)u << 32) |
                      (unsigned long long)(0xFFFFFFFFu - (unsigned)i);
      }
      bool eq = (i < cN) && (u == P);
      if (eq) {
        unsigned pe = atomicAdd(&sh_E, 0u);  // dummy read to keep sh_E live
        (void)pe;
      }
    }
    __syncthreads();
    // collect equal indices (separate pass, low traffic)
    if (tid == 0) sh_E = 0u;
    __syncthreads();
    for (int i0 = 0; i0 < cN; i0 += 1024) {
      int i = i0 + tid;
      unsigned u = (i < cN) ? uk[i] : 0u;
      bool eq = (i < cN) && (u == P);
      unsigned long long mb = __ballot(eq);
      if (eq) {
        int ldr = __ffsll((long long)mb) - 1;
        unsigned base = 0;
        if (lane == ldr) base = atomicAdd(&sh_E, (unsigned)__popcll(mb));
        base = __shfl(base, ldr);
        unsigned pos = base + (unsigned)__popcll(mb & ((1ull << lane) - 1ull));
        if (pos < 1024u) eqbuf[pos] = (unsigned)i;
      }
    }
    __syncthreads();
    sort1024_u32_asc(eqbuf, tid);
    int need = (int)cK - (int)gtc;
    for (int t = tid; t < need; t += 1024) {
      unsigned idx = eqbuf[t];
      if (idx != 0xFFFFFFFFu)
        cand[gtc + (unsigned)t] = ((unsigned long long)P << 32) |
                                  (unsigned long long)(0xFFFFFFFFu - idx);
    }
    __syncthreads();
  }

  // rank-by-count: distinct keys -> rank is a permutation of 0..1023
  unsigned long long my = cand[tid];
  unsigned rk = 0;
#pragma unroll 8
  for (int j = 0; j < 1024; ++j) rk += (cand[j] > my) ? 1u : 0u;
  if (rk < (unsigned)cK) {
    unsigned uhi = (unsigned)(my >> 32);
    int idx = (int)(0xFFFFFFFFu - (unsigned)(my & 0xFFFFFFFFull));
    topidx[img * cK + (int)rk] = (uhi > 0u) ? idx : -1;
  }
}

// ---------------- kernel 3: gather ----------------
__global__ __launch_bounds__(256) void k_gather(const float* __restrict__ in,
                                                const int* __restrict__ topidx,
                                                float4* __restrict__ boxes,
                                                float* __restrict__ area,
                                                float* __restrict__ objv,
                                                float* __restrict__ confv,
                                                int* __restrict__ clsv,
                                                int* __restrict__ validv) {
  int wid = (int)((blockIdx.x * 256u + threadIdx.x) >> 6);
  int lane = threadIdx.x & 63;
  if (wid >= cB * cK) return;
  int img = wid / cK;
  int idx = topidx[wid];
  if (idx < 0) {
    if (lane == 0) {
      boxes[wid] = make_float4(0.f, 0.f, 0.f, 0.f);
      area[wid] = 0.f; objv[wid] = 0.f; confv[wid] = 0.f;
      clsv[wid] = -1; validv[wid] = 0;
    }
    return;
  }
  const float* row = in + ((size_t)img * cN + (size_t)idx) * cROW;
  float v = row[5 + lane];
  int ci = lane;
  if (lane < 16) {
    float v2 = row[69 + lane];
    if (v2 > v) { v = v2; ci = 64 + lane; }
  }
#pragma unroll
  for (int m = 1; m < 64; m <<= 1) {
    float ov = __shfl_xor(v, m);
    int oc = __shfl_xor(ci, m);
    if (ov > v || (ov == v && oc < ci)) { v = ov; ci = oc; }
  }
  if (lane == 0) {
    float cx = row[0], cy = row[1], w = row[2], h = row[3], ob = row[4];
    float hw = w * 0.5f, hh = h * 0.5f;
    float x1 = cx - hw, y1 = cy - hh, x2 = cx + hw, y2 = cy + hh;
    boxes[wid] = make_float4(x1, y1, x2, y2);
    area[wid] = fmaxf(x2 - x1, 0.f) * fmaxf(y2 - y1, 0.f);
    objv[wid] = ob; confv[wid] = v; clsv[wid] = ci; validv[wid] = 1;
  }
}

// ---------------- kernel 4: suppress bitmask, TRANSPOSED output ----------------
// St[img][w][i] (i padded to 1024): word w of suppress-row i.
__global__ __launch_bounds__(256) void k_suppress(const float4* __restrict__ boxes,
                                                  const float* __restrict__ area,
                                                  const int* __restrict__ clsv,
                                                  unsigned* __restrict__ St) {
  // +(i>>5) padding: inner-loop bank = (w+bit)%32 -> conflict-free
  __shared__ float sx1[1056], sy1[1056], sx2[1056], sy2[1056], sar[1056];
  __shared__ int scls[1056];
  int img = blockIdx.x >> 7;            // / 128
  int rb = (blockIdx.x & 127) * 8;      // 128 blocks x 8 rows = 1024 rows
  int tid = threadIdx.x;
  for (int i = tid; i < 1024; i += 256) {
    int p = i + (i >> 5);
    if (i < cK) {
      float4 b = boxes[img * cK + i];
      sx1[p] = b.x; sy1[p] = b.y; sx2[p] = b.z; sy2[p] = b.w;
      sar[p] = area[img * cK + i];
      scls[p] = clsv[img * cK + i];
    } else {
      sx1[p] = 0.f; sy1[p] = 0.f; sx2[p] = 0.f; sy2[p] = 0.f; sar[p] = 0.f;
      scls[p] = -2;
    }
  }
  __syncthreads();
  int i = rb + (tid >> 5);
  int w = tid & 31;
  int pi = i + (i >> 5);
  float bx1 = sx1[pi], by1 = sy1[pi], bx2 = sx2[pi], by2 = sy2[pi], ba = sar[pi];
  int bc = scls[pi];
  unsigned word = 0u;
#pragma unroll 4
  for (int bit = 0; bit < 32; ++bit) {
    int pj = 33 * w + bit;
    float xx1 = fmaxf(bx1, sx1[pj]);
    float yy1 = fmaxf(by1, sy1[pj]);
    float xx2 = fminf(bx2, sx2[pj]);
    float yy2 = fminf(by2, sy2[pj]);
    float inter = fmaxf(xx2 - xx1, 0.f) * fmaxf(yy2 - yy1, 0.f);
    float uni = ba + sar[pj] - inter;
    float iou = inter / (uni + 1e-16f);
    if (iou > NMS_T && bc == scls[pj]) word |= (1u << bit);
  }
  St[((size_t)(img * 32 + w)) * 1024 + (size_t)i] = word;
}

// ---------------- kernel 5: word-batched greedy NMS + masked write ----------------
// All buffer accesses use compile-time indices (no runtime-selected pointer) so
// bufA/bufB stay in VGPRs. R3's pointer-switch version spilled to scratch
// (VGPR_Count=28 -> 131 us).
__device__ __forceinline__ unsigned u4c(const uint4& v, int c) {
  return c == 0 ? v.x : c == 1 ? v.y : c == 2 ? v.z : v.w;
}

__device__ __forceinline__ void nms_load(const uint4* __restrict__ colv, int b,
                                         uint4 (&buf)[8]) {
#pragma unroll
  for (int q = 0; q < 8; ++q) buf[q] = colv[8 * b + q];
}

__device__ __forceinline__ void nms_proc(int b, int lane, unsigned& kw,
                                         const uint4 (&W)[8]) {
  unsigned dec = 0u;
  if (lane == b) {
    unsigned kwb = kw;
#pragma unroll
    for (int t = 0; t < 32; ++t) {
      if ((kwb >> t) & 1u) {
        dec |= (1u << t);
        unsigned rw = u4c(W[t >> 2], t & 3);
        unsigned mgt = (t == 31) ? 0u : (0xFFFFFFFFu << (t + 1));
        kwb &= ~(rw & mgt);   // kill only later rows within this word
      }
    }
    kw = kwb;
  }
  dec = __shfl(dec, b);       // broadcast the 32 decisions
  if (lane > b) {
#pragma unroll
    for (int t = 0; t < 32; ++t) {
      unsigned sel = 0u - ((dec >> t) & 1u);
      kw &= ~(u4c(W[t >> 2], t & 3) & sel);
    }
  }
}

__global__ __launch_bounds__(64) void k_nms(const unsigned* __restrict__ St,
                                            const int* __restrict__ validv,
                                            const float4* __restrict__ boxes,
                                            const float* __restrict__ objv,
                                            const float* __restrict__ confv,
                                            const int* __restrict__ clsv,
                                            float* __restrict__ out) {
  __shared__ unsigned keep_sh[32];
  int img = blockIdx.x;
  int lane = threadIdx.x;
  if (lane < 32) {
    const uint4* colv = (const uint4*)(St + ((size_t)(img * 32 + lane)) * 1024);
    unsigned kw = 0u;
    for (int b = 0; b < 32; ++b) {
      int k = (lane << 5) + b;
      if (k < cK && validv[img * cK + k]) kw |= (1u << b);
    }
    uint4 bufA[8], bufB[8];
    nms_load(colv, 0, bufA);
    for (int b = 0; b < 32; b += 2) {
      if (b + 1 < 32) nms_load(colv, b + 1, bufB);
      nms_proc(b, lane, kw, bufA);
      if (b + 2 < 32) nms_load(colv, b + 2, bufA);
      nms_proc(b + 1, lane, kw, bufB);
    }
    keep_sh[lane] = kw;
  }
  __syncthreads();
  for (int k = lane; k < cK; k += 64) {
    bool kp = ((keep_sh[k >> 5] >> (k & 31)) & 1u) != 0u;
    size_t o = ((size_t)img * cK + (size_t)k) * 7;
    if (kp) {
      float4 b = boxes[img * cK + k];
      out[o + 0] = b.x; out[o + 1] = b.y; out[o + 2] = b.z; out[o + 3] = b.w;
      out[o + 4] = objv[img * cK + k];
      out[o + 5] = confv[img * cK + k];
      out[o + 6] = (float)clsv[img * cK + k];
    } else {
      out[o + 0] = 0.f; out[o + 1] = 0.f; out[o + 2] = 0.f; out[o + 3] = 0.f;
      out[o + 4] = 0.f; out[o + 5] = 0.f; out[o + 6] = 0.f;
    }
  }
}

extern "C" void kernel_launch(void* const* d_in, const int* in_sizes, int n_in,
                              void* d_out, int out_size, void* d_ws, size_t ws_size,
                              hipStream_t stream) {
  const float* in = (const float*)d_in[0];
  float* out = (float*)d_out;
  char* ws = (char*)d_ws;
  size_t off = 0;
  auto take = [&](size_t bytes) {
    size_t r = off;
    off += (bytes + 255) & ~(size_t)255;
    return r;
  };
  unsigned* ukey = (unsigned*)(ws + take((size_t)cB * cN * 4));
  int* topidx = (int*)(ws + take((size_t)cB * cK * 4));
  float4* boxes = (float4*)(ws + take((size_t)cB * cK * 16));
  float* area = (float*)(ws + take((size_t)cB * cK * 4));
  float* objv = (float*)(ws + take((size_t)cB * cK * 4));
  float* confv = (float*)(ws + take((size_t)cB * cK * 4));
  int* clsv = (int*)(ws + take((size_t)cB * cK * 4));
  int* validv = (int*)(ws + take((size_t)cB * cK * 4));
  unsigned* St = (unsigned*)(ws + take((size_t)cB * 32 * 1024 * 4));

  int nrows = cB * cN;
  int blocks1 = (nrows + 127) / 128;          // 128 rows per block
  k_score<<<blocks1, 256, 0, stream>>>(in, ukey);
  k_topk<<<cB, 1024, 0, stream>>>(ukey, topidx);
  int waves3 = cB * cK;
  k_gather<<<(waves3 * 64 + 255) / 256, 256, 0, stream>>>(in, topidx, boxes, area,
                                                          objv, confv, clsv, validv);
  k_suppress<<<cB * 128, 256, 0, stream>>>(boxes, area, clsv, St);
  k_nms<<<cB, 64, 0, stream>>>(St, validv, boxes, objv, confv, clsv, out);
}

// Round 7
// 281.809 us; speedup vs baseline: 2.0026x; 1.0103x over previous
//
#include <hip/hip_runtime.h>
#include <cstdint>

#pragma clang fp contract(off)

constexpr int cB = 16;
constexpr int cN = 22743;
constexpr int cROW = 85;
constexpr int cK = 1000;
constexpr float CONF_T = 0.5f;
constexpr float NMS_T = 0.4f;

// ---------------- kernel 1: per-row score -> orderable uint key ----------------
// Stage 128 rows into LDS coalesced; TWO threads per row, 4-accumulator ILP
// (chain depth 80 -> ~12), pair-combine via one shfl_xor. R6's one-thread-per-row
// version was latency-bound on an 80-deep dependent fmax chain with half the
// block idle.
__global__ __launch_bounds__(256) void k_score(const float* __restrict__ in,
                                               unsigned* __restrict__ ukey) {
  __shared__ float sdata[10880];              // 128 rows x 85 floats = 43.52 KB
  constexpr int F4_PER_BLK = 2720;            // 10880 / 4
  constexpr int TOTAL_F4 = (cB * cN * cROW) / 4;
  int tid = threadIdx.x;
  const float4* gin4 = (const float4*)in;
  float4* s4 = (float4*)sdata;
  int base_f4 = blockIdx.x * F4_PER_BLK;
#pragma unroll
  for (int q = 0; q < 11; ++q) {
    int k = tid + 256 * q;
    if (k < F4_PER_BLK) {
      int g = base_f4 + k;
      if (g < TOTAL_F4) s4[k] = gin4[g];
    }
  }
  __syncthreads();
  int r = tid >> 1, h = tid & 1;              // pair (2r,2r+1) -> row r
  int grow = blockIdx.x * 128 + r;
  if (grow < cB * cN) {
    const float* rowp = sdata + cROW * r;
    int j0 = 5 + h * 40;                      // h=0: classes 0..39, h=1: 40..79
    float m0 = rowp[j0 + 0], m1 = rowp[j0 + 1];
    float m2 = rowp[j0 + 2], m3 = rowp[j0 + 3];
#pragma unroll
    for (int k = 4; k < 40; k += 4) {
      m0 = fmaxf(m0, rowp[j0 + k + 0]);
      m1 = fmaxf(m1, rowp[j0 + k + 1]);
      m2 = fmaxf(m2, rowp[j0 + k + 2]);
      m3 = fmaxf(m3, rowp[j0 + k + 3]);
    }
    float m = fmaxf(fmaxf(m0, m1), fmaxf(m2, m3));
    m = fmaxf(m, __shfl_xor(m, 1));           // partner lane = same row, other half
    if (h == 0) {
      float obj = rowp[4];
      unsigned u = 0u;
      if (obj >= CONF_T) {
        float s = obj * m;
        if (s > 0.0f) u = __float_as_uint(s);
      }
      ukey[grow] = u;
    }
  }
}

// ---------------- bitonic sort (u32 asc; only for the rare exact-tie path) ----
__device__ __forceinline__ void sort1024_u32_asc(unsigned* a, int tid) {
  for (int k = 2; k <= 1024; k <<= 1) {
    for (int j = k >> 1; j >= 1; j >>= 1) {
      __syncthreads();
      if (tid < 512) {
        int i = ((tid & ~(j - 1)) << 1) | (tid & (j - 1));
        int p = i | j;
        unsigned x = a[i], y = a[p];
        bool up = ((i & k) == 0);
        bool sw = up ? (x > y) : (x < y);
        if (sw) { a[i] = y; a[p] = x; }
      }
    }
  }
  __syncthreads();
}

// ---------------- kernel 2: exact top-1000 per image ----------------
// 11-bit histogram radix-select (1 round typical), hierarchical 3-barrier scan
// (R6's Hillis-Steele used 20 barriers of a 16-wave block), compaction,
// rank-by-count emit.
__global__ __launch_bounds__(1024) void k_topk(const unsigned* __restrict__ ukey,
                                               int* __restrict__ topidx) {
  __shared__ unsigned hist[2048];             // 8 KB
  __shared__ unsigned wtot[16];
  __shared__ unsigned long long cand[1024];   // 8 KB
  __shared__ unsigned eqbuf[1024];            // 4 KB (tie path only)
  __shared__ unsigned sh_T, sh_newrank, sh_E, sh_cnt;
  int img = blockIdx.x;
  int tid = threadIdx.x;
  int lane = tid & 63;
  int wv = tid >> 6;
  const unsigned* uk = ukey + (size_t)img * cN;

  unsigned prefix = 0;
  int bits = 0;
  unsigned rank = cK;
  unsigned gtc = 0;   // count of keys strictly greater than current prefix block
  unsigned E = 0;     // count of keys equal to current prefix block

  for (int r = 0; r < 3; ++r) {
    int nb = (r < 2) ? 11 : 10;
    int shift = 32 - bits - nb;
    hist[tid] = 0u; hist[tid + 1024] = 0u;
    __syncthreads();
    for (int i0 = 0; i0 < cN; i0 += 1024) {
      int i = i0 + tid;
      unsigned u = (i < cN) ? uk[i] : 0u;
      bool inr = (i < cN);
      bool match = inr && (bits == 0 || (u >> (32 - bits)) == prefix);
      bool isz = match && (u == 0u);
      bool nz = match && (u != 0u);
      // zeros all hit bin 0 -> aggregate to one atomic per wave
      unsigned long long mz = __ballot(isz);
      if (isz && lane == (__ffsll((long long)mz) - 1))
        atomicAdd(&hist[0], (unsigned)__popcll(mz));
      if (nz) atomicAdd(&hist[(u >> shift) & ((1u << nb) - 1u)], 1u);
    }
    __syncthreads();
    // hierarchical suffix scan over 2048 bins: pair-sum -> in-wave shfl suffix
    // -> 16 wave totals -> broadcast add. 3 barriers total.
    unsigned h0 = hist[2 * tid];
    unsigned h1 = hist[2 * tid + 1];
    unsigned s2 = h0 + h1;
#pragma unroll
    for (int s = 1; s < 64; s <<= 1) {
      unsigned t = __shfl_down(s2, s);
      s2 += (lane + s < 64) ? t : 0u;
    }
    if (lane == 0) wtot[wv] = s2;             // wave total (inclusive suffix at lane 0)
    __syncthreads();
    unsigned above = 0;
    for (int w2 = wv + 1; w2 < 16; ++w2) above += wtot[w2];
    unsigned S_even = above + s2;             // suffix(bin 2*tid)
    unsigned S_odd = S_even - h0;             // suffix(bin 2*tid+1)
    unsigned S_next = S_odd - h1;             // suffix(bin 2*tid+2); 0 at tid=1023
    if (S_even >= rank && S_odd < rank) { sh_T = 2u * tid; sh_newrank = rank - S_odd; sh_E = h0; }
    if (S_odd >= rank && S_next < rank) { sh_T = 2u * tid + 1u; sh_newrank = rank - S_next; sh_E = h1; }
    __syncthreads();
    unsigned T = sh_T;
    unsigned nr = sh_newrank;
    E = sh_E;
    gtc += rank - nr;
    rank = nr;
    prefix = (prefix << nb) | T;
    bits += nb;
    __syncthreads();           // hist reused next round
    if (gtc + E <= 1024u) break;
  }

  bool tiepath = (gtc + E > 1024u);   // only possible at bits==32 (exact ties)
  unsigned pivotLo = (bits >= 32) ? prefix : (prefix << (32 - bits));
  cand[tid] = (unsigned long long)tid;   // distinct filler keys, high32 = 0
  eqbuf[tid] = 0xFFFFFFFFu;
  if (tid == 0) sh_cnt = 0u;
  __syncthreads();

  if (!tiepath) {
    for (int i0 = 0; i0 < cN; i0 += 1024) {
      int i = i0 + tid;
      unsigned u = (i < cN) ? uk[i] : 0u;
      bool m = (i < cN) && (u >= pivotLo);
      unsigned long long mb = __ballot(m);
      if (m) {
        int ldr = __ffsll((long long)mb) - 1;
        unsigned base = 0;
        if (lane == ldr) base = atomicAdd(&sh_cnt, (unsigned)__popcll(mb));
        base = __shfl(base, ldr);
        unsigned pos = base + (unsigned)__popcll(mb & ((1ull << lane) - 1ull));
        if (pos < 1024u)
          cand[pos] = ((unsigned long long)u << 32) |
                      (unsigned long long)(0xFFFFFFFFu - (unsigned)i);
      }
    }
    __syncthreads();
  } else {
    // exact-tie fallback: u > P into cand, u == P smallest indices appended
    unsigned P = prefix;
    for (int i0 = 0; i0 < cN; i0 += 1024) {
      int i = i0 + tid;
      unsigned u = (i < cN) ? uk[i] : 0u;
      bool gt = (i < cN) && (u > P);
      unsigned long long mb = __ballot(gt);
      if (gt) {
        int ldr = __ffsll((long long)mb) - 1;
        unsigned base = 0;
        if (lane == ldr) base = atomicAdd(&sh_cnt, (unsigned)__popcll(mb));
        base = __shfl(base, ldr);
        unsigned pos = base + (unsigned)__popcll(mb & ((1ull << lane) - 1ull));
        if (pos < 1024u)
          cand[pos] = ((unsigned long long)u << 32) |
                      (unsigned long long)(0xFFFFFFFFu - (unsigned)i);
      }
    }
    __syncthreads();
    if (tid == 0) sh_E = 0u;
    __syncthreads();
    for (int i0 = 0; i0 < cN; i0 += 1024) {
      int i = i0 + tid;
      unsigned u = (i < cN) ? uk[i] : 0u;
      bool eq = (i < cN) && (u == P);
      unsigned long long mb = __ballot(eq);
      if (eq) {
        int ldr = __ffsll((long long)mb) - 1;
        unsigned base = 0;
        if (lane == ldr) base = atomicAdd(&sh_E, (unsigned)__popcll(mb));
        base = __shfl(base, ldr);
        unsigned pos = base + (unsigned)__popcll(mb & ((1ull << lane) - 1ull));
        if (pos < 1024u) eqbuf[pos] = (unsigned)i;
      }
    }
    __syncthreads();
    sort1024_u32_asc(eqbuf, tid);
    int need = (int)cK - (int)gtc;
    for (int t = tid; t < need; t += 1024) {
      unsigned idx = eqbuf[t];
      if (idx != 0xFFFFFFFFu)
        cand[gtc + (unsigned)t] = ((unsigned long long)P << 32) |
                                  (unsigned long long)(0xFFFFFFFFu - idx);
    }
    __syncthreads();
  }

  // rank-by-count: distinct keys -> rank is a permutation of 0..1023
  unsigned long long my = cand[tid];
  unsigned rk = 0;
#pragma unroll 8
  for (int j = 0; j < 1024; ++j) rk += (cand[j] > my) ? 1u : 0u;
  if (rk < (unsigned)cK) {
    unsigned uhi = (unsigned)(my >> 32);
    int idx = (int)(0xFFFFFFFFu - (unsigned)(my & 0xFFFFFFFFull));
    topidx[img * cK + (int)rk] = (uhi > 0u) ? idx : -1;
  }
}

// ---------------- kernel 3: gather ----------------
__global__ __launch_bounds__(256) void k_gather(const float* __restrict__ in,
                                                const int* __restrict__ topidx,
                                                float4* __restrict__ boxes,
                                                float* __restrict__ area,
                                                float* __restrict__ objv,
                                                float* __restrict__ confv,
                                                int* __restrict__ clsv,
                                                int* __restrict__ validv) {
  int wid = (int)((blockIdx.x * 256u + threadIdx.x) >> 6);
  int lane = threadIdx.x & 63;
  if (wid >= cB * cK) return;
  int img = wid / cK;
  int idx = topidx[wid];
  if (idx < 0) {
    if (lane == 0) {
      boxes[wid] = make_float4(0.f, 0.f, 0.f, 0.f);
      area[wid] = 0.f; objv[wid] = 0.f; confv[wid] = 0.f;
      clsv[wid] = -1; validv[wid] = 0;
    }
    return;
  }
  const float* row = in + ((size_t)img * cN + (size_t)idx) * cROW;
  float v = row[5 + lane];
  int ci = lane;
  if (lane < 16) {
    float v2 = row[69 + lane];
    if (v2 > v) { v = v2; ci = 64 + lane; }
  }
#pragma unroll
  for (int m = 1; m < 64; m <<= 1) {
    float ov = __shfl_xor(v, m);
    int oc = __shfl_xor(ci, m);
    if (ov > v || (ov == v && oc < ci)) { v = ov; ci = oc; }
  }
  if (lane == 0) {
    float cx = row[0], cy = row[1], w = row[2], h = row[3], ob = row[4];
    float hw = w * 0.5f, hh = h * 0.5f;
    float x1 = cx - hw, y1 = cy - hh, x2 = cx + hw, y2 = cy + hh;
    boxes[wid] = make_float4(x1, y1, x2, y2);
    area[wid] = fmaxf(x2 - x1, 0.f) * fmaxf(y2 - y1, 0.f);
    objv[wid] = ob; confv[wid] = v; clsv[wid] = ci; validv[wid] = 1;
  }
}

// ---------------- kernel 4: suppress bitmask, TRANSPOSED output ----------------
// St[img][w][i] (i padded to 1024): word w of suppress-row i.
__global__ __launch_bounds__(256) void k_suppress(const float4* __restrict__ boxes,
                                                  const float* __restrict__ area,
                                                  const int* __restrict__ clsv,
                                                  unsigned* __restrict__ St) {
  // +(i>>5) padding: inner-loop bank = (w+bit)%32 -> conflict-free
  __shared__ float sx1[1056], sy1[1056], sx2[1056], sy2[1056], sar[1056];
  __shared__ int scls[1056];
  int img = blockIdx.x >> 7;            // / 128
  int rb = (blockIdx.x & 127) * 8;      // 128 blocks x 8 rows = 1024 rows
  int tid = threadIdx.x;
  for (int i = tid; i < 1024; i += 256) {
    int p = i + (i >> 5);
    if (i < cK) {
      float4 b = boxes[img * cK + i];
      sx1[p] = b.x; sy1[p] = b.y; sx2[p] = b.z; sy2[p] = b.w;
      sar[p] = area[img * cK + i];
      scls[p] = clsv[img * cK + i];
    } else {
      sx1[p] = 0.f; sy1[p] = 0.f; sx2[p] = 0.f; sy2[p] = 0.f; sar[p] = 0.f;
      scls[p] = -2;
    }
  }
  __syncthreads();
  int i = rb + (tid >> 5);
  int w = tid & 31;
  int pi = i + (i >> 5);
  float bx1 = sx1[pi], by1 = sy1[pi], bx2 = sx2[pi], by2 = sy2[pi], ba = sar[pi];
  int bc = scls[pi];
  unsigned word = 0u;
#pragma unroll 4
  for (int bit = 0; bit < 32; ++bit) {
    int pj = 33 * w + bit;
    float xx1 = fmaxf(bx1, sx1[pj]);
    float yy1 = fmaxf(by1, sy1[pj]);
    float xx2 = fminf(bx2, sx2[pj]);
    float yy2 = fminf(by2, sy2[pj]);
    float inter = fmaxf(xx2 - xx1, 0.f) * fmaxf(yy2 - yy1, 0.f);
    float uni = ba + sar[pj] - inter;
    float iou = inter / (uni + 1e-16f);
    if (iou > NMS_T && bc == scls[pj]) word |= (1u << bit);
  }
  St[((size_t)(img * 32 + w)) * 1024 + (size_t)i] = word;
}

// ---------------- kernel 5: word-batched greedy NMS + masked write ----------------
// All buffer accesses use compile-time indices (no runtime-selected pointer) so
// bufA/bufB stay in VGPRs. R3's pointer-switch version spilled to scratch
// (VGPR_Count=28 -> 131 us).
__device__ __forceinline__ unsigned u4c(const uint4& v, int c) {
  return c == 0 ? v.x : c == 1 ? v.y : c == 2 ? v.z : v.w;
}

__device__ __forceinline__ void nms_load(const uint4* __restrict__ colv, int b,
                                         uint4 (&buf)[8]) {
#pragma unroll
  for (int q = 0; q < 8; ++q) buf[q] = colv[8 * b + q];
}

__device__ __forceinline__ void nms_proc(int b, int lane, unsigned& kw,
                                         const uint4 (&W)[8]) {
  unsigned dec = 0u;
  if (lane == b) {
    unsigned kwb = kw;
#pragma unroll
    for (int t = 0; t < 32; ++t) {
      if ((kwb >> t) & 1u) {
        dec |= (1u << t);
        unsigned rw = u4c(W[t >> 2], t & 3);
        unsigned mgt = (t == 31) ? 0u : (0xFFFFFFFFu << (t + 1));
        kwb &= ~(rw & mgt);   // kill only later rows within this word
      }
    }
    kw = kwb;
  }
  dec = __shfl(dec, b);       // broadcast the 32 decisions
  if (lane > b) {
#pragma unroll
    for (int t = 0; t < 32; ++t) {
      unsigned sel = 0u - ((dec >> t) & 1u);
      kw &= ~(u4c(W[t >> 2], t & 3) & sel);
    }
  }
}

__global__ __launch_bounds__(64) void k_nms(const unsigned* __restrict__ St,
                                            const int* __restrict__ validv,
                                            const float4* __restrict__ boxes,
                                            const float* __restrict__ objv,
                                            const float* __restrict__ confv,
                                            const int* __restrict__ clsv,
                                            float* __restrict__ out) {
  __shared__ unsigned keep_sh[32];
  int img = blockIdx.x;
  int lane = threadIdx.x;
  if (lane < 32) {
    const uint4* colv = (const uint4*)(St + ((size_t)(img * 32 + lane)) * 1024);
    unsigned kw = 0u;
    for (int b = 0; b < 32; ++b) {
      int k = (lane << 5) + b;
      if (k < cK && validv[img * cK + k]) kw |= (1u << b);
    }
    uint4 bufA[8], bufB[8];
    nms_load(colv, 0, bufA);
    for (int b = 0; b < 32; b += 2) {
      if (b + 1 < 32) nms_load(colv, b + 1, bufB);
      nms_proc(b, lane, kw, bufA);
      if (b + 2 < 32) nms_load(colv, b + 2, bufA);
      nms_proc(b + 1, lane, kw, bufB);
    }
    keep_sh[lane] = kw;
  }
  __syncthreads();
  for (int k = lane; k < cK; k += 64) {
    bool kp = ((keep_sh[k >> 5] >> (k & 31)) & 1u) != 0u;
    size_t o = ((size_t)img * cK + (size_t)k) * 7;
    if (kp) {
      float4 b = boxes[img * cK + k];
      out[o + 0] = b.x; out[o + 1] = b.y; out[o + 2] = b.z; out[o + 3] = b.w;
      out[o + 4] = objv[img * cK + k];
      out[o + 5] = confv[img * cK + k];
      out[o + 6] = (float)clsv[img * cK + k];
    } else {
      out[o + 0] = 0.f; out[o + 1] = 0.f; out[o + 2] = 0.f; out[o + 3] = 0.f;
      out[o + 4] = 0.f; out[o + 5] = 0.f; out[o + 6] = 0.f;
    }
  }
}

extern "C" void kernel_launch(void* const* d_in, const int* in_sizes, int n_in,
                              void* d_out, int out_size, void* d_ws, size_t ws_size,
                              hipStream_t stream) {
  const float* in = (const float*)d_in[0];
  float* out = (float*)d_out;
  char* ws = (char*)d_ws;
  size_t off = 0;
  auto take = [&](size_t bytes) {
    size_t r = off;
    off += (bytes + 255) & ~(size_t)255;
    return r;
  };
  unsigned* ukey = (unsigned*)(ws + take((size_t)cB * cN * 4));
  int* topidx = (int*)(ws + take((size_t)cB * cK * 4));
  float4* boxes = (float4*)(ws + take((size_t)cB * cK * 16));
  float* area = (float*)(ws + take((size_t)cB * cK * 4));
  float* objv = (float*)(ws + take((size_t)cB * cK * 4));
  float* confv = (float*)(ws + take((size_t)cB * cK * 4));
  int* clsv = (int*)(ws + take((size_t)cB * cK * 4));
  int* validv = (int*)(ws + take((size_t)cB * cK * 4));
  unsigned* St = (unsigned*)(ws + take((size_t)cB * 32 * 1024 * 4));

  int nrows = cB * cN;
  int blocks1 = (nrows + 127) / 128;          // 128 rows per block
  k_score<<<blocks1, 256, 0, stream>>>(in, ukey);
  k_topk<<<cB, 1024, 0, stream>>>(ukey, topidx);
  int waves3 = cB * cK;
  k_gather<<<(waves3 * 64 + 255) / 256, 256, 0, stream>>>(in, topidx, boxes, area,
                                                          objv, confv, clsv, validv);
  k_suppress<<<cB * 128, 256, 0, stream>>>(boxes, area, clsv, St);
  k_nms<<<cB, 64, 0, stream>>>(St, validv, boxes, objv, confv, clsv, out);
}